// Round 9
// baseline (357.746 us; speedup 1.0000x reference)
//
#include <hip/hip_runtime.h>
#include <hip/hip_bf16.h>

#define NEG_SLOPE 0.2f

typedef short bf16x8 __attribute__((ext_vector_type(8)));
typedef float f32x4 __attribute__((ext_vector_type(4)));
typedef float f32x2 __attribute__((ext_vector_type(2)));

__device__ __forceinline__ unsigned short f2bf(float f) {
    unsigned int x = __float_as_uint(f);
    unsigned int lsb = (x >> 16) & 1u;
    x += 0x7fffu + lsb;
    return (unsigned short)(x >> 16);
}
__device__ __forceinline__ f32x2 upk(unsigned int u) {
    f32x2 r;
    r.x = __uint_as_float(u << 16);
    r.y = __uint_as_float(u & 0xffff0000u);
    return r;
}
__device__ __forceinline__ unsigned short f2h(float f) {
    _Float16 h = (_Float16)f;
    return *(unsigned short*)&h;
}
__device__ __forceinline__ float h2f(unsigned short u) {
    _Float16 h = *(_Float16*)&u;
    return (float)h;
}

// ---------------- W casts (both weights, one launch) ----------------
__global__ void cast_w_both(const float* __restrict__ W1, const float* __restrict__ W2,
                            unsigned short* __restrict__ wt1, unsigned short* __restrict__ wt2) {
    int idx = blockIdx.x * 256 + threadIdx.x;
    if (idx < 128 * 256) {
        int k = idx >> 8, n = idx & 255;
        wt1[(size_t)n * 128 + k] = f2bf(W1[idx]);
    } else {
        int j = idx - 128 * 256;
        int k = j >> 7, n = j & 127;
        wt2[(size_t)n * 256 + k] = f2bf(W2[j]);
    }
}

// ---------------- CSR build ----------------
__global__ void degree_kernel(const int* __restrict__ ei, int E, int N,
                              int* __restrict__ deg, int* __restrict__ idx) {
    int e = blockIdx.x * blockDim.x + threadIdx.x;
    int EA = E + N;
    if (e >= EA) return;
    int dst = (e < E) ? ei[E + e] : (e - E);
    idx[e] = atomicAdd(&deg[dst], 1);
}

__global__ void scan_local(const int* __restrict__ deg, int* __restrict__ offs,
                           int* __restrict__ bsum, int N) {
    __shared__ int wsum[16];
    int tid = threadIdx.x;
    int lane = tid & 63;
    int wave = tid >> 6;
    int i = blockIdx.x * 1024 + tid;
    int v = (i < N) ? deg[i] : 0;
    int x = v;
    #pragma unroll
    for (int off = 1; off < 64; off <<= 1) {
        int t = __shfl_up(x, off);
        if (lane >= off) x += t;
    }
    if (lane == 63) wsum[wave] = x;
    __syncthreads();
    if (wave == 0 && lane < 16) {
        int w = wsum[lane];
        #pragma unroll
        for (int off = 1; off < 16; off <<= 1) {
            int t = __shfl_up(w, off);
            if (lane >= off) w += t;
        }
        wsum[lane] = w;
    }
    __syncthreads();
    int wexcl = (wave > 0) ? wsum[wave - 1] : 0;
    if (i <= N) offs[i] = wexcl + x - v;
    if (tid == 0) bsum[blockIdx.x] = wsum[15];
}

__global__ void scan_add(int* __restrict__ offs, const int* __restrict__ bsum,
                         int N, int nb) {
    int lane = threadIdx.x & 63;
    int v = (lane < nb) ? bsum[lane] : 0;
    int x = v;
    #pragma unroll
    for (int off = 1; off < 64; off <<= 1) {
        int t = __shfl_up(x, off);
        if (lane >= off) x += t;
    }
    int excl = __shfl(x - v, blockIdx.x);
    int i = blockIdx.x * 1024 + threadIdx.x;
    if (i <= N) offs[i] += excl;
}

// scatter (no atomics) + fused layer-1 edge-weight precompute (fp16 x4)
__global__ void scatter_kernel(const int* __restrict__ ei, int E, int N,
                               const int* __restrict__ offs, const int* __restrict__ idx,
                               const float* __restrict__ as1, const float* __restrict__ ad1,
                               int* __restrict__ colb, uint2* __restrict__ p1) {
    int e = blockIdx.x * blockDim.x + threadIdx.x;
    int EA = E + N;
    if (e >= EA) return;
    int s, d;
    if (e < E) { s = ei[e]; d = ei[E + e]; }
    else       { s = d = e - E; }
    int pos = offs[d] + idx[e];
    colb[pos] = s << 9;
    float4 av = *(const float4*)(as1 + s * 4);
    float4 dv = *(const float4*)(ad1 + d * 4);
    float e0 = av.x + dv.x, e1 = av.y + dv.y, e2 = av.z + dv.z, e3 = av.w + dv.w;
    e0 = (e0 > 0.f) ? e0 : NEG_SLOPE * e0;
    e1 = (e1 > 0.f) ? e1 : NEG_SLOPE * e1;
    e2 = (e2 > 0.f) ? e2 : NEG_SLOPE * e2;
    e3 = (e3 > 0.f) ? e3 : NEG_SLOPE * e3;
    uint2 q;
    q.x = (unsigned int)f2h(__expf(e0)) | ((unsigned int)f2h(__expf(e1)) << 16);
    q.y = (unsigned int)f2h(__expf(e2)) | ((unsigned int)f2h(__expf(e3)) << 16);
    p1[pos] = q;
}

// layer-2 edge weights (after gemm2): p2[pos] = exp(leaky(as2[s] + ad2[d]))
__global__ void edgew2_kernel(const int* __restrict__ ei, int E, int N,
                              const int* __restrict__ offs, const int* __restrict__ idx,
                              const float* __restrict__ as2, const float* __restrict__ ad2,
                              float* __restrict__ p2) {
    int e = blockIdx.x * blockDim.x + threadIdx.x;
    int EA = E + N;
    if (e >= EA) return;
    int s, d;
    if (e < E) { s = ei[e]; d = ei[E + e]; }
    else       { s = d = e - E; }
    int pos = offs[d] + idx[e];
    float ev = as2[s] + ad2[d];
    ev = (ev > 0.f) ? ev : NEG_SLOPE * ev;
    p2[pos] = __expf(ev);
}

// ---------------- MFMA GEMM1 + fused x-cast + fused alpha1 ----------------
// 128 rows/block, 32 rows/wave (2 row-tiles share each B fragment).
__global__ void gemm1_mfma(const float* __restrict__ A,
                           const unsigned short* __restrict__ Wt,
                           const float* __restrict__ att_s, const float* __restrict__ att_d,
                           unsigned short* __restrict__ hb,
                           float* __restrict__ as, float* __restrict__ ad, int M) {
    int wave = threadIdx.x >> 6;
    int lane = threadIdx.x & 63;
    int quad = lane >> 4;
    int l16 = lane & 15;
    int m0 = blockIdx.x * 128 + wave * 32;
    int r0c = min(m0 + l16, M - 1);
    int r1c = min(m0 + 16 + l16, M - 1);
    bf16x8 a0[4], a1[4];
    #pragma unroll
    for (int kc = 0; kc < 4; ++kc) {
        const float* p0 = A + (size_t)r0c * 128 + quad * 8 + kc * 32;
        const float* p1 = A + (size_t)r1c * 128 + quad * 8 + kc * 32;
        float4 f0 = *(const float4*)(p0);
        float4 f1 = *(const float4*)(p0 + 4);
        float4 g0 = *(const float4*)(p1);
        float4 g1 = *(const float4*)(p1 + 4);
        bf16x8 v0, v1;
        v0[0] = (short)f2bf(f0.x); v0[1] = (short)f2bf(f0.y);
        v0[2] = (short)f2bf(f0.z); v0[3] = (short)f2bf(f0.w);
        v0[4] = (short)f2bf(f1.x); v0[5] = (short)f2bf(f1.y);
        v0[6] = (short)f2bf(f1.z); v0[7] = (short)f2bf(f1.w);
        v1[0] = (short)f2bf(g0.x); v1[1] = (short)f2bf(g0.y);
        v1[2] = (short)f2bf(g0.z); v1[3] = (short)f2bf(g0.w);
        v1[4] = (short)f2bf(g1.x); v1[5] = (short)f2bf(g1.y);
        v1[6] = (short)f2bf(g1.z); v1[7] = (short)f2bf(g1.w);
        a0[kc] = v0; a1[kc] = v1;
    }
    f32x4 acc0[16], acc1[16];
    #pragma unroll
    for (int nt = 0; nt < 16; ++nt) {
        f32x4 c0 = {0.f, 0.f, 0.f, 0.f};
        f32x4 c1 = {0.f, 0.f, 0.f, 0.f};
        const unsigned short* bp = Wt + (size_t)(nt * 16 + l16) * 128 + quad * 8;
        #pragma unroll
        for (int kc = 0; kc < 4; ++kc) {
            bf16x8 b = *(const bf16x8*)(bp + kc * 32);
            c0 = __builtin_amdgcn_mfma_f32_16x16x32_bf16(a0[kc], b, c0, 0, 0, 0);
            c1 = __builtin_amdgcn_mfma_f32_16x16x32_bf16(a1[kc], b, c1, 0, 0, 0);
        }
        acc0[nt] = c0; acc1[nt] = c1;
    }
    float asv[16], adv[16];
    #pragma unroll
    for (int nt = 0; nt < 16; ++nt) {
        asv[nt] = att_s[nt * 16 + l16];
        adv[nt] = att_d[nt * 16 + l16];
    }
    #pragma unroll
    for (int g = 0; g < 2; ++g) {
        f32x4* acc = g ? acc1 : acc0;
        int srow0 = m0 + g * 16 + quad * 4;
        #pragma unroll
        for (int r = 0; r < 4; ++r) {
            int srow = srow0 + r;
            bool ok = srow < M;
            if (ok) {
                #pragma unroll
                for (int nt = 0; nt < 16; ++nt)
                    hb[(size_t)srow * 256 + nt * 16 + l16] = f2bf(acc[nt][r]);
            }
            #pragma unroll
            for (int h = 0; h < 4; ++h) {
                float ps = acc[4 * h][r] * asv[4 * h] + acc[4 * h + 1][r] * asv[4 * h + 1]
                         + acc[4 * h + 2][r] * asv[4 * h + 2] + acc[4 * h + 3][r] * asv[4 * h + 3];
                float pd = acc[4 * h][r] * adv[4 * h] + acc[4 * h + 1][r] * adv[4 * h + 1]
                         + acc[4 * h + 2][r] * adv[4 * h + 2] + acc[4 * h + 3][r] * adv[4 * h + 3];
                #pragma unroll
                for (int off = 1; off < 16; off <<= 1) {
                    ps += __shfl_xor(ps, off);
                    pd += __shfl_xor(pd, off);
                }
                if (ok && l16 == 0) {
                    as[srow * 4 + h] = ps;
                    ad[srow * 4 + h] = pd;
                }
            }
        }
    }
}

// ---------------- MFMA GEMM2 + fused alpha2 (32 rows/wave) ----------------
__global__ void gemm2_mfma(const unsigned short* __restrict__ Ab,
                           const unsigned short* __restrict__ Wt,
                           const float* __restrict__ att_s, const float* __restrict__ att_d,
                           unsigned short* __restrict__ hb,
                           float* __restrict__ as, float* __restrict__ ad, int M) {
    int wave = threadIdx.x >> 6;
    int lane = threadIdx.x & 63;
    int quad = lane >> 4;
    int l16 = lane & 15;
    int m0 = blockIdx.x * 128 + wave * 32;
    int r0c = min(m0 + l16, M - 1);
    int r1c = min(m0 + 16 + l16, M - 1);
    bf16x8 a0[8], a1[8];
    const unsigned short* ap0 = Ab + (size_t)r0c * 256 + quad * 8;
    const unsigned short* ap1 = Ab + (size_t)r1c * 256 + quad * 8;
    #pragma unroll
    for (int kc = 0; kc < 8; ++kc) {
        a0[kc] = *(const bf16x8*)(ap0 + kc * 32);
        a1[kc] = *(const bf16x8*)(ap1 + kc * 32);
    }
    f32x4 acc0[8], acc1[8];
    #pragma unroll
    for (int nt = 0; nt < 8; ++nt) {
        f32x4 c0 = {0.f, 0.f, 0.f, 0.f};
        f32x4 c1 = {0.f, 0.f, 0.f, 0.f};
        const unsigned short* bp = Wt + (size_t)(nt * 16 + l16) * 256 + quad * 8;
        #pragma unroll
        for (int kc = 0; kc < 8; ++kc) {
            bf16x8 b = *(const bf16x8*)(bp + kc * 32);
            c0 = __builtin_amdgcn_mfma_f32_16x16x32_bf16(a0[kc], b, c0, 0, 0, 0);
            c1 = __builtin_amdgcn_mfma_f32_16x16x32_bf16(a1[kc], b, c1, 0, 0, 0);
        }
        acc0[nt] = c0; acc1[nt] = c1;
    }
    float asv[8], adv[8];
    #pragma unroll
    for (int nt = 0; nt < 8; ++nt) {
        asv[nt] = att_s[nt * 16 + l16];
        adv[nt] = att_d[nt * 16 + l16];
    }
    #pragma unroll
    for (int g = 0; g < 2; ++g) {
        f32x4* acc = g ? acc1 : acc0;
        int srow0 = m0 + g * 16 + quad * 4;
        #pragma unroll
        for (int r = 0; r < 4; ++r) {
            int srow = srow0 + r;
            bool ok = srow < M;
            if (ok) {
                #pragma unroll
                for (int nt = 0; nt < 8; ++nt)
                    hb[(size_t)srow * 128 + nt * 16 + l16] = f2bf(acc[nt][r]);
            }
            float ps = 0.f, pd = 0.f;
            #pragma unroll
            for (int nt = 0; nt < 8; ++nt) {
                ps = fmaf(acc[nt][r], asv[nt], ps);
                pd = fmaf(acc[nt][r], adv[nt], pd);
            }
            #pragma unroll
            for (int off = 1; off < 16; off <<= 1) {
                ps += __shfl_xor(ps, off);
                pd += __shfl_xor(pd, off);
            }
            if (ok && l16 == 0) { as[srow] = ps; ad[srow] = pd; }
        }
    }
}

// ---------------- layer-1 aggregation ----------------
__global__ void agg1_kernel(const unsigned short* __restrict__ hb,
                            const int* __restrict__ colb, const uint2* __restrict__ p1,
                            const int* __restrict__ offs,
                            const float* __restrict__ b1,
                            unsigned short* __restrict__ out, int N) {
    int node = blockIdx.x * 4 + (threadIdx.x >> 6);
    if (node >= N) return;
    int lane = threadIdx.x & 63;
    int half = lane >> 5;
    int sub  = lane & 31;
    int head = sub >> 3;
    int c0b = sub * 16;
    const char* hpc = (const char*)hb;
    int beg = offs[node], end = offs[node + 1];
    float d = 0.f;
    f32x2 acc[4] = {};
    int j = beg + half;
    for (; j + 6 < end; j += 8) {
        int o0 = colb[j] + c0b;
        int o1 = colb[j + 2] + c0b;
        int o2 = colb[j + 4] + c0b;
        int o3 = colb[j + 6] + c0b;
        uint2 q0 = p1[j];
        uint2 q1 = p1[j + 2];
        uint2 q2 = p1[j + 4];
        uint2 q3 = p1[j + 6];
        uint4 g0 = *(const uint4*)(hpc + o0);
        uint4 g1 = *(const uint4*)(hpc + o1);
        uint4 g2 = *(const uint4*)(hpc + o2);
        uint4 g3 = *(const uint4*)(hpc + o3);
        unsigned int u0 = (head & 2) ? q0.y : q0.x;
        unsigned int u1 = (head & 2) ? q1.y : q1.x;
        unsigned int u2 = (head & 2) ? q2.y : q2.x;
        unsigned int u3 = (head & 2) ? q3.y : q3.x;
        float p0 = h2f((unsigned short)((head & 1) ? (u0 >> 16) : (u0 & 0xffff)));
        float p1v = h2f((unsigned short)((head & 1) ? (u1 >> 16) : (u1 & 0xffff)));
        float p2 = h2f((unsigned short)((head & 1) ? (u2 >> 16) : (u2 & 0xffff)));
        float p3 = h2f((unsigned short)((head & 1) ? (u3 >> 16) : (u3 & 0xffff)));
        d += (p0 + p1v) + (p2 + p3);
        const unsigned int* w0 = (const unsigned int*)&g0;
        const unsigned int* w1 = (const unsigned int*)&g1;
        const unsigned int* w2 = (const unsigned int*)&g2;
        const unsigned int* w3 = (const unsigned int*)&g3;
        f32x2 v0 = {p0, p0}, v1 = {p1v, p1v}, v2 = {p2, p2}, v3 = {p3, p3};
        #pragma unroll
        for (int i = 0; i < 4; ++i) {
            acc[i] = __builtin_elementwise_fma(v0, upk(w0[i]), acc[i]);
            acc[i] = __builtin_elementwise_fma(v1, upk(w1[i]), acc[i]);
            acc[i] = __builtin_elementwise_fma(v2, upk(w2[i]), acc[i]);
            acc[i] = __builtin_elementwise_fma(v3, upk(w3[i]), acc[i]);
        }
    }
    for (; j < end; j += 2) {
        int o = colb[j] + c0b;
        uint2 q = p1[j];
        uint4 g = *(const uint4*)(hpc + o);
        unsigned int u = (head & 2) ? q.y : q.x;
        float p = h2f((unsigned short)((head & 1) ? (u >> 16) : (u & 0xffff)));
        d += p;
        const unsigned int* w = (const unsigned int*)&g;
        f32x2 v = {p, p};
        #pragma unroll
        for (int i = 0; i < 4; ++i)
            acc[i] = __builtin_elementwise_fma(v, upk(w[i]), acc[i]);
    }
    d += __shfl_xor(d, 32);
    #pragma unroll
    for (int i = 0; i < 4; ++i) {
        acc[i].x += __shfl_xor(acc[i].x, 32);
        acc[i].y += __shfl_xor(acc[i].y, 32);
    }
    if (half == 0) {
        float inv = 1.f / d;
        int c0 = sub * 8;
        float4 bb0 = *(const float4*)(b1 + c0);
        float4 bb1 = *(const float4*)(b1 + c0 + 4);
        float av[8] = {acc[0].x, acc[0].y, acc[1].x, acc[1].y,
                       acc[2].x, acc[2].y, acc[3].x, acc[3].y};
        float bb[8] = {bb0.x, bb0.y, bb0.z, bb0.w, bb1.x, bb1.y, bb1.z, bb1.w};
        unsigned short o[8];
        #pragma unroll
        for (int i = 0; i < 8; ++i) {
            float v = av[i] * inv + bb[i];
            v = (v > 0.f) ? v : (__expf(v) - 1.f);
            o[i] = f2bf(v);
        }
        ushort4 q0 = {o[0], o[1], o[2], o[3]};
        ushort4 q1 = {o[4], o[5], o[6], o[7]};
        *(ushort4*)(out + (size_t)node * 256 + c0) = q0;
        *(ushort4*)(out + (size_t)node * 256 + c0 + 4) = q1;
    }
}

// ---------------- layer-2 aggregation (precomputed p2) ----------------
__global__ void agg2_kernel(const unsigned short* __restrict__ hb,
                            const float* __restrict__ p2,
                            const int* __restrict__ offs, const int* __restrict__ colb,
                            const float* __restrict__ b2,
                            float* __restrict__ out, int N) {
    int node = blockIdx.x * 4 + (threadIdx.x >> 6);
    if (node >= N) return;
    int lane = threadIdx.x & 63;
    int q   = lane >> 4;
    int sub = lane & 15;
    int c0b = sub * 16;
    const char* hpc = (const char*)hb;
    int beg = offs[node], end = offs[node + 1];
    float d = 0.f;
    f32x2 acc[4] = {};
    int j = beg + q;
    for (; j + 4 < end; j += 8) {
        int cb0 = colb[j];
        int cb1 = colb[j + 4];
        float p0 = p2[j];
        float p1 = p2[j + 4];
        uint4 g0 = *(const uint4*)(hpc + (cb0 >> 1) + c0b);
        uint4 g1 = *(const uint4*)(hpc + (cb1 >> 1) + c0b);
        d += p0 + p1;
        const unsigned int* w0 = (const unsigned int*)&g0;
        const unsigned int* w1 = (const unsigned int*)&g1;
        f32x2 v0 = {p0, p0}, v1 = {p1, p1};
        #pragma unroll
        for (int i = 0; i < 4; ++i) {
            acc[i] = __builtin_elementwise_fma(v0, upk(w0[i]), acc[i]);
            acc[i] = __builtin_elementwise_fma(v1, upk(w1[i]), acc[i]);
        }
    }
    for (; j < end; j += 4) {
        int cb = colb[j];
        float p = p2[j];
        uint4 g = *(const uint4*)(hpc + (cb >> 1) + c0b);
        d += p;
        const unsigned int* w = (const unsigned int*)&g;
        f32x2 v = {p, p};
        #pragma unroll
        for (int i = 0; i < 4; ++i)
            acc[i] = __builtin_elementwise_fma(v, upk(w[i]), acc[i]);
    }
    d += __shfl_xor(d, 16);
    d += __shfl_xor(d, 32);
    #pragma unroll
    for (int i = 0; i < 4; ++i) {
        acc[i].x += __shfl_xor(acc[i].x, 16);
        acc[i].x += __shfl_xor(acc[i].x, 32);
        acc[i].y += __shfl_xor(acc[i].y, 16);
        acc[i].y += __shfl_xor(acc[i].y, 32);
    }
    if (lane < 16) {
        float inv = 1.f / d;
        int c0 = sub * 8;
        float4 bb0 = *(const float4*)(b2 + c0);
        float4 bb1 = *(const float4*)(b2 + c0 + 4);
        float av[8] = {acc[0].x, acc[0].y, acc[1].x, acc[1].y,
                       acc[2].x, acc[2].y, acc[3].x, acc[3].y};
        float bb[8] = {bb0.x, bb0.y, bb0.z, bb0.w, bb1.x, bb1.y, bb1.z, bb1.w};
        *(float4*)(out + (size_t)node * 128 + c0) =
            make_float4(av[0] * inv + bb[0], av[1] * inv + bb[1],
                        av[2] * inv + bb[2], av[3] * inv + bb[3]);
        *(float4*)(out + (size_t)node * 128 + c0 + 4) =
            make_float4(av[4] * inv + bb[4], av[5] * inv + bb[5],
                        av[6] * inv + bb[6], av[7] * inv + bb[7]);
    }
}

// ---------------- launch ----------------

extern "C" void kernel_launch(void* const* d_in, const int* in_sizes, int n_in,
                              void* d_out, int out_size, void* d_ws, size_t ws_size,
                              hipStream_t stream) {
    const float* x    = (const float*)d_in[0];
    const int*   ei   = (const int*)d_in[1];
    const float* W1   = (const float*)d_in[2];
    const float* at_s1 = (const float*)d_in[3];
    const float* at_d1 = (const float*)d_in[4];
    const float* b1   = (const float*)d_in[5];
    const float* W2   = (const float*)d_in[6];
    const float* at_s2 = (const float*)d_in[7];
    const float* at_d2 = (const float*)d_in[8];
    const float* b2   = (const float*)d_in[9];
    float* out = (float*)d_out;

    const int N  = in_sizes[0] / 128;
    const int E  = in_sizes[1] / 2;
    const int EA = E + N;

    char* ws = (char*)d_ws;
    size_t off = 0;
    auto alloc = [&](size_t bytes) -> void* {
        void* p = ws + off;
        off += (bytes + 255) & ~(size_t)255;
        return p;
    };
    unsigned short* wt1  = (unsigned short*)alloc((size_t)256 * 128 * 2);
    unsigned short* wt2  = (unsigned short*)alloc((size_t)128 * 256 * 2);
    unsigned short* h1b  = (unsigned short*)alloc((size_t)N * 256 * 2);
    unsigned short* h1ab = (unsigned short*)alloc((size_t)N * 256 * 2);
    unsigned short* h2b  = (unsigned short*)alloc((size_t)N * 128 * 2);
    float* as1 = (float*)alloc((size_t)N * 4 * 4);
    float* ad1 = (float*)alloc((size_t)N * 4 * 4);
    float* as2 = (float*)alloc((size_t)N * 4);
    float* ad2 = (float*)alloc((size_t)N * 4);
    int* deg  = (int*)alloc((size_t)N * 4);
    int* idx  = (int*)alloc((size_t)EA * 4);
    int* offs = (int*)alloc((size_t)(N + 1) * 4);
    int* bsum = (int*)alloc((size_t)1024 * 4);
    int* colb = (int*)alloc((size_t)EA * 4);
    uint2* p1 = (uint2*)alloc((size_t)EA * 8);
    float* p2 = (float*)alloc((size_t)EA * 4);

    const int nb = (N + 1 + 1023) / 1024;

    hipMemsetAsync(deg, 0, (size_t)N * 4, stream);
    cast_w_both<<<(2 * 128 * 256 + 255) / 256, 256, 0, stream>>>(W1, W2, wt1, wt2);
    degree_kernel<<<(EA + 255) / 256, 256, 0, stream>>>(ei, E, N, deg, idx);
    scan_local<<<nb, 1024, 0, stream>>>(deg, offs, bsum, N);
    scan_add<<<nb, 1024, 0, stream>>>(offs, bsum, N, nb);

    gemm1_mfma<<<(N + 127) / 128, 256, 0, stream>>>(x, wt1, at_s1, at_d1, h1b, as1, ad1, N);
    scatter_kernel<<<(EA + 255) / 256, 256, 0, stream>>>(ei, E, N, offs, idx, as1, ad1,
                                                         colb, p1);
    agg1_kernel<<<(N + 3) / 4, 256, 0, stream>>>(h1b, colb, p1, offs, b1, h1ab, N);

    gemm2_mfma<<<(N + 127) / 128, 256, 0, stream>>>(h1ab, wt2, at_s2, at_d2, h2b, as2, ad2, N);
    edgew2_kernel<<<(EA + 255) / 256, 256, 0, stream>>>(ei, E, N, offs, idx, as2, ad2, p2);
    agg2_kernel<<<(N + 3) / 4, 256, 0, stream>>>(h2b, p2, offs, colb, b2, out, N);
}

// Round 10
// 348.795 us; speedup vs baseline: 1.0257x; 1.0257x over previous
//
#include <hip/hip_runtime.h>
#include <hip/hip_bf16.h>

#define NEG_SLOPE 0.2f

typedef short bf16x8 __attribute__((ext_vector_type(8)));
typedef float f32x4 __attribute__((ext_vector_type(4)));
typedef float f32x2 __attribute__((ext_vector_type(2)));

__device__ __forceinline__ unsigned short f2bf(float f) {
    unsigned int x = __float_as_uint(f);
    unsigned int lsb = (x >> 16) & 1u;
    x += 0x7fffu + lsb;
    return (unsigned short)(x >> 16);
}
__device__ __forceinline__ f32x2 upk(unsigned int u) {
    f32x2 r;
    r.x = __uint_as_float(u << 16);
    r.y = __uint_as_float(u & 0xffff0000u);
    return r;
}
__device__ __forceinline__ unsigned short f2h(float f) {
    _Float16 h = (_Float16)f;
    return *(unsigned short*)&h;
}
__device__ __forceinline__ float h2f(unsigned short u) {
    _Float16 h = *(_Float16*)&u;
    return (float)h;
}

// ---------------- W casts ----------------
// wt1[n][k] plain. wt2's k-axis uses h1's pi-permutation: pi(c)= (c&15)*16 + (c>>4)
// i.e. k-position p corresponds to original channel c(p) = (p&15)*16 + (p>>4).
__global__ void cast_w_both(const float* __restrict__ W1, const float* __restrict__ W2,
                            unsigned short* __restrict__ wt1, unsigned short* __restrict__ wt2) {
    int idx = blockIdx.x * 256 + threadIdx.x;
    if (idx < 128 * 256) {
        int k = idx >> 8, n = idx & 255;
        wt1[(size_t)n * 128 + k] = f2bf(W1[idx]);
    } else {
        int j = idx - 128 * 256;
        int n = j >> 8;          // 0..127
        int p = j & 255;         // permuted k position
        int c = (p & 15) * 16 + (p >> 4);
        wt2[(size_t)n * 256 + p] = f2bf(W2[(size_t)c * 128 + n]);
    }
}

// ---------------- CSR build ----------------
__global__ void degree_kernel(const int* __restrict__ ei, int E, int N,
                              int* __restrict__ deg, int* __restrict__ idx) {
    int e = blockIdx.x * blockDim.x + threadIdx.x;
    int EA = E + N;
    if (e >= EA) return;
    int dst = (e < E) ? ei[E + e] : (e - E);
    idx[e] = atomicAdd(&deg[dst], 1);
}

__global__ void scan_local(const int* __restrict__ deg, int* __restrict__ offs,
                           int* __restrict__ bsum, int N) {
    __shared__ int wsum[16];
    int tid = threadIdx.x;
    int lane = tid & 63;
    int wave = tid >> 6;
    int i = blockIdx.x * 1024 + tid;
    int v = (i < N) ? deg[i] : 0;
    int x = v;
    #pragma unroll
    for (int off = 1; off < 64; off <<= 1) {
        int t = __shfl_up(x, off);
        if (lane >= off) x += t;
    }
    if (lane == 63) wsum[wave] = x;
    __syncthreads();
    if (wave == 0 && lane < 16) {
        int w = wsum[lane];
        #pragma unroll
        for (int off = 1; off < 16; off <<= 1) {
            int t = __shfl_up(w, off);
            if (lane >= off) w += t;
        }
        wsum[lane] = w;
    }
    __syncthreads();
    int wexcl = (wave > 0) ? wsum[wave - 1] : 0;
    if (i <= N) offs[i] = wexcl + x - v;
    if (tid == 0) bsum[blockIdx.x] = wsum[15];
}

__global__ void scan_add(int* __restrict__ offs, const int* __restrict__ bsum,
                         int N, int nb) {
    int lane = threadIdx.x & 63;
    int v = (lane < nb) ? bsum[lane] : 0;
    int x = v;
    #pragma unroll
    for (int off = 1; off < 64; off <<= 1) {
        int t = __shfl_up(x, off);
        if (lane >= off) x += t;
    }
    int excl = __shfl(x - v, blockIdx.x);
    int i = blockIdx.x * 1024 + threadIdx.x;
    if (i <= N) offs[i] += excl;
}

// scatter (no atomics) + fused layer-1 edge-weight precompute (fp16 x4)
__global__ void scatter_kernel(const int* __restrict__ ei, int E, int N,
                               const int* __restrict__ offs, const int* __restrict__ idx,
                               const float* __restrict__ as1, const float* __restrict__ ad1,
                               int* __restrict__ colb, uint2* __restrict__ p1) {
    int e = blockIdx.x * blockDim.x + threadIdx.x;
    int EA = E + N;
    if (e >= EA) return;
    int s, d;
    if (e < E) { s = ei[e]; d = ei[E + e]; }
    else       { s = d = e - E; }
    int pos = offs[d] + idx[e];
    colb[pos] = s << 9;
    float4 av = *(const float4*)(as1 + s * 4);
    float4 dv = *(const float4*)(ad1 + d * 4);
    float e0 = av.x + dv.x, e1 = av.y + dv.y, e2 = av.z + dv.z, e3 = av.w + dv.w;
    e0 = (e0 > 0.f) ? e0 : NEG_SLOPE * e0;
    e1 = (e1 > 0.f) ? e1 : NEG_SLOPE * e1;
    e2 = (e2 > 0.f) ? e2 : NEG_SLOPE * e2;
    e3 = (e3 > 0.f) ? e3 : NEG_SLOPE * e3;
    uint2 q;
    q.x = (unsigned int)f2h(__expf(e0)) | ((unsigned int)f2h(__expf(e1)) << 16);
    q.y = (unsigned int)f2h(__expf(e2)) | ((unsigned int)f2h(__expf(e3)) << 16);
    p1[pos] = q;
}

// layer-2 edge weights: p2[pos] = exp(leaky(as2[s] + ad2[d]))
__global__ void edgew2_kernel(const int* __restrict__ ei, int E, int N,
                              const int* __restrict__ offs, const int* __restrict__ idx,
                              const float* __restrict__ as2, const float* __restrict__ ad2,
                              float* __restrict__ p2) {
    int e = blockIdx.x * blockDim.x + threadIdx.x;
    int EA = E + N;
    if (e >= EA) return;
    int s, d;
    if (e < E) { s = ei[e]; d = ei[E + e]; }
    else       { s = d = e - E; }
    int pos = offs[d] + idx[e];
    float ev = as2[s] + ad2[d];
    ev = (ev > 0.f) ? ev : NEG_SLOPE * ev;
    p2[pos] = __expf(ev);
}

// ---------------- MFMA GEMM1 + fused x-cast + fused alpha1 ----------------
// 64 rows/block, 16 rows/wave (R8 shape). hb stored PERMUTED: channel
// c = nt*16+l16 lands at pi-position l16*16+nt -> lane stores 16 contiguous
// shorts (2x16B, fully coalesced per quad).
__global__ void gemm1_mfma(const float* __restrict__ A,
                           const unsigned short* __restrict__ Wt,
                           const float* __restrict__ att_s, const float* __restrict__ att_d,
                           unsigned short* __restrict__ hb,
                           float* __restrict__ as, float* __restrict__ ad, int M) {
    int wave = threadIdx.x >> 6;
    int lane = threadIdx.x & 63;
    int quad = lane >> 4;
    int l16 = lane & 15;
    int m0 = blockIdx.x * 64 + wave * 16;
    int rowc = min(m0 + l16, M - 1);
    bf16x8 a[4];
    const float* ap = A + (size_t)rowc * 128 + quad * 8;
    #pragma unroll
    for (int kc = 0; kc < 4; ++kc) {
        float4 f0 = *(const float4*)(ap + kc * 32);
        float4 f1 = *(const float4*)(ap + kc * 32 + 4);
        bf16x8 v;
        v[0] = (short)f2bf(f0.x); v[1] = (short)f2bf(f0.y);
        v[2] = (short)f2bf(f0.z); v[3] = (short)f2bf(f0.w);
        v[4] = (short)f2bf(f1.x); v[5] = (short)f2bf(f1.y);
        v[6] = (short)f2bf(f1.z); v[7] = (short)f2bf(f1.w);
        a[kc] = v;
    }
    f32x4 acc[16];
    #pragma unroll
    for (int nt = 0; nt < 16; ++nt) {
        f32x4 c = {0.f, 0.f, 0.f, 0.f};
        const unsigned short* bp = Wt + (size_t)(nt * 16 + l16) * 128 + quad * 8;
        #pragma unroll
        for (int kc = 0; kc < 4; ++kc) {
            bf16x8 b = *(const bf16x8*)(bp + kc * 32);
            c = __builtin_amdgcn_mfma_f32_16x16x32_bf16(a[kc], b, c, 0, 0, 0);
        }
        acc[nt] = c;
    }
    float asv[16], adv[16];
    #pragma unroll
    for (int nt = 0; nt < 16; ++nt) {
        asv[nt] = att_s[nt * 16 + l16];
        adv[nt] = att_d[nt * 16 + l16];
    }
    int srow0 = m0 + quad * 4;
    #pragma unroll
    for (int r = 0; r < 4; ++r) {
        int srow = srow0 + r;
        bool ok = srow < M;
        if (ok) {
            unsigned int pk[8];
            #pragma unroll
            for (int i = 0; i < 8; ++i)
                pk[i] = (unsigned int)f2bf(acc[2 * i][r]) |
                        ((unsigned int)f2bf(acc[2 * i + 1][r]) << 16);
            uint4 lo = {pk[0], pk[1], pk[2], pk[3]};
            uint4 hi = {pk[4], pk[5], pk[6], pk[7]};
            *(uint4*)(hb + (size_t)srow * 256 + l16 * 16) = lo;
            *(uint4*)(hb + (size_t)srow * 256 + l16 * 16 + 8) = hi;
        }
        #pragma unroll
        for (int h = 0; h < 4; ++h) {
            float ps = acc[4 * h][r] * asv[4 * h] + acc[4 * h + 1][r] * asv[4 * h + 1]
                     + acc[4 * h + 2][r] * asv[4 * h + 2] + acc[4 * h + 3][r] * asv[4 * h + 3];
            float pd = acc[4 * h][r] * adv[4 * h] + acc[4 * h + 1][r] * adv[4 * h + 1]
                     + acc[4 * h + 2][r] * adv[4 * h + 2] + acc[4 * h + 3][r] * adv[4 * h + 3];
            #pragma unroll
            for (int off = 1; off < 16; off <<= 1) {
                ps += __shfl_xor(ps, off);
                pd += __shfl_xor(pd, off);
            }
            if (ok && l16 == 0) {
                as[srow * 4 + h] = ps;
                ad[srow * 4 + h] = pd;
            }
        }
    }
}

// ---------------- MFMA GEMM2 + fused alpha2 (R8 shape) ----------------
// A (h1ab) is in pi-space; wt2's k-axis matches. Output store unpermuted.
__global__ void gemm2_mfma(const unsigned short* __restrict__ Ab,
                           const unsigned short* __restrict__ Wt,
                           const float* __restrict__ att_s, const float* __restrict__ att_d,
                           unsigned short* __restrict__ hb,
                           float* __restrict__ as, float* __restrict__ ad, int M) {
    int wave = threadIdx.x >> 6;
    int lane = threadIdx.x & 63;
    int quad = lane >> 4;
    int l16 = lane & 15;
    int m0 = blockIdx.x * 64 + wave * 16;
    int rowc = min(m0 + l16, M - 1);
    bf16x8 a[8];
    const unsigned short* ap = Ab + (size_t)rowc * 256 + quad * 8;
    #pragma unroll
    for (int kc = 0; kc < 8; ++kc) a[kc] = *(const bf16x8*)(ap + kc * 32);
    f32x4 acc[8];
    #pragma unroll
    for (int nt = 0; nt < 8; ++nt) {
        f32x4 c = {0.f, 0.f, 0.f, 0.f};
        const unsigned short* bp = Wt + (size_t)(nt * 16 + l16) * 256 + quad * 8;
        #pragma unroll
        for (int kc = 0; kc < 8; ++kc) {
            bf16x8 b = *(const bf16x8*)(bp + kc * 32);
            c = __builtin_amdgcn_mfma_f32_16x16x32_bf16(a[kc], b, c, 0, 0, 0);
        }
        acc[nt] = c;
    }
    float asv[8], adv[8];
    #pragma unroll
    for (int nt = 0; nt < 8; ++nt) {
        asv[nt] = att_s[nt * 16 + l16];
        adv[nt] = att_d[nt * 16 + l16];
    }
    int srow0 = m0 + quad * 4;
    #pragma unroll
    for (int r = 0; r < 4; ++r) {
        int srow = srow0 + r;
        bool ok = srow < M;
        if (ok) {
            #pragma unroll
            for (int nt = 0; nt < 8; ++nt)
                hb[(size_t)srow * 128 + nt * 16 + l16] = f2bf(acc[nt][r]);
        }
        float ps = 0.f, pd = 0.f;
        #pragma unroll
        for (int nt = 0; nt < 8; ++nt) {
            ps = fmaf(acc[nt][r], asv[nt], ps);
            pd = fmaf(acc[nt][r], adv[nt], pd);
        }
        #pragma unroll
        for (int off = 1; off < 16; off <<= 1) {
            ps += __shfl_xor(ps, off);
            pd += __shfl_xor(pd, off);
        }
        if (ok && l16 == 0) { as[srow] = ps; ad[srow] = pd; }
    }
}

// ---------------- layer-1 aggregation (pi-space) ----------------
// Lane sub covers pi-positions sub*8..+7, which span TWO heads:
// i<4 -> head 2*(sub&1), i>=4 -> head 2*(sub&1)+1. Two p-weights + two denoms.
__global__ void agg1_kernel(const unsigned short* __restrict__ hb,
                            const int* __restrict__ colb, const uint2* __restrict__ p1,
                            const int* __restrict__ offs,
                            const float* __restrict__ b1,
                            unsigned short* __restrict__ out, int N) {
    int node = blockIdx.x * 4 + (threadIdx.x >> 6);
    if (node >= N) return;
    int lane = threadIdx.x & 63;
    int half = lane >> 5;
    int sub  = lane & 31;
    int c0b = sub * 16;
    const char* hpc = (const char*)hb;
    int beg = offs[node], end = offs[node + 1];
    float dL = 0.f, dH = 0.f;
    f32x2 acc[4] = {};
    int j = beg + half;
    for (; j + 6 < end; j += 8) {
        int o0 = colb[j] + c0b;
        int o1 = colb[j + 2] + c0b;
        int o2 = colb[j + 4] + c0b;
        int o3 = colb[j + 6] + c0b;
        uint2 q0 = p1[j];
        uint2 q1 = p1[j + 2];
        uint2 q2 = p1[j + 4];
        uint2 q3 = p1[j + 6];
        uint4 g0 = *(const uint4*)(hpc + o0);
        uint4 g1 = *(const uint4*)(hpc + o1);
        uint4 g2 = *(const uint4*)(hpc + o2);
        uint4 g3 = *(const uint4*)(hpc + o3);
        unsigned int u0 = (sub & 1) ? q0.y : q0.x;
        unsigned int u1 = (sub & 1) ? q1.y : q1.x;
        unsigned int u2 = (sub & 1) ? q2.y : q2.x;
        unsigned int u3 = (sub & 1) ? q3.y : q3.x;
        float pL0 = h2f((unsigned short)(u0 & 0xffff)), pH0 = h2f((unsigned short)(u0 >> 16));
        float pL1 = h2f((unsigned short)(u1 & 0xffff)), pH1 = h2f((unsigned short)(u1 >> 16));
        float pL2 = h2f((unsigned short)(u2 & 0xffff)), pH2 = h2f((unsigned short)(u2 >> 16));
        float pL3 = h2f((unsigned short)(u3 & 0xffff)), pH3 = h2f((unsigned short)(u3 >> 16));
        dL += (pL0 + pL1) + (pL2 + pL3);
        dH += (pH0 + pH1) + (pH2 + pH3);
        const unsigned int* w0 = (const unsigned int*)&g0;
        const unsigned int* w1 = (const unsigned int*)&g1;
        const unsigned int* w2 = (const unsigned int*)&g2;
        const unsigned int* w3 = (const unsigned int*)&g3;
        f32x2 vL0 = {pL0, pL0}, vH0 = {pH0, pH0};
        f32x2 vL1 = {pL1, pL1}, vH1 = {pH1, pH1};
        f32x2 vL2 = {pL2, pL2}, vH2 = {pH2, pH2};
        f32x2 vL3 = {pL3, pL3}, vH3 = {pH3, pH3};
        #pragma unroll
        for (int i = 0; i < 2; ++i) {
            acc[i] = __builtin_elementwise_fma(vL0, upk(w0[i]), acc[i]);
            acc[i] = __builtin_elementwise_fma(vL1, upk(w1[i]), acc[i]);
            acc[i] = __builtin_elementwise_fma(vL2, upk(w2[i]), acc[i]);
            acc[i] = __builtin_elementwise_fma(vL3, upk(w3[i]), acc[i]);
            acc[i + 2] = __builtin_elementwise_fma(vH0, upk(w0[i + 2]), acc[i + 2]);
            acc[i + 2] = __builtin_elementwise_fma(vH1, upk(w1[i + 2]), acc[i + 2]);
            acc[i + 2] = __builtin_elementwise_fma(vH2, upk(w2[i + 2]), acc[i + 2]);
            acc[i + 2] = __builtin_elementwise_fma(vH3, upk(w3[i + 2]), acc[i + 2]);
        }
    }
    for (; j < end; j += 2) {
        int o = colb[j] + c0b;
        uint2 q = p1[j];
        uint4 g = *(const uint4*)(hpc + o);
        unsigned int u = (sub & 1) ? q.y : q.x;
        float pL = h2f((unsigned short)(u & 0xffff));
        float pH = h2f((unsigned short)(u >> 16));
        dL += pL;
        dH += pH;
        const unsigned int* w = (const unsigned int*)&g;
        f32x2 vL = {pL, pL}, vH = {pH, pH};
        #pragma unroll
        for (int i = 0; i < 2; ++i) {
            acc[i] = __builtin_elementwise_fma(vL, upk(w[i]), acc[i]);
            acc[i + 2] = __builtin_elementwise_fma(vH, upk(w[i + 2]), acc[i + 2]);
        }
    }
    dL += __shfl_xor(dL, 32);
    dH += __shfl_xor(dH, 32);
    #pragma unroll
    for (int i = 0; i < 4; ++i) {
        acc[i].x += __shfl_xor(acc[i].x, 32);
        acc[i].y += __shfl_xor(acc[i].y, 32);
    }
    if (half == 0) {
        float invL = 1.f / dL;
        float invH = 1.f / dH;
        float av[8] = {acc[0].x, acc[0].y, acc[1].x, acc[1].y,
                       acc[2].x, acc[2].y, acc[3].x, acc[3].y};
        unsigned short o[8];
        int base16 = sub >> 1;            // c(q) = (8*(sub&1)+i)*16 + (sub>>1)
        int lo16 = 8 * (sub & 1);
        #pragma unroll
        for (int i = 0; i < 8; ++i) {
            float inv = (i < 4) ? invL : invH;
            float bbv = b1[(lo16 + i) * 16 + base16];
            float v = av[i] * inv + bbv;
            v = (v > 0.f) ? v : (__expf(v) - 1.f);
            o[i] = f2bf(v);
        }
        ushort4 q0 = {o[0], o[1], o[2], o[3]};
        ushort4 q1 = {o[4], o[5], o[6], o[7]};
        *(ushort4*)(out + (size_t)node * 256 + sub * 8) = q0;
        *(ushort4*)(out + (size_t)node * 256 + sub * 8 + 4) = q1;
    }
}

// ---------------- layer-2 aggregation (precomputed p2) ----------------
__global__ void agg2_kernel(const unsigned short* __restrict__ hb,
                            const float* __restrict__ p2,
                            const int* __restrict__ offs, const int* __restrict__ colb,
                            const float* __restrict__ b2,
                            float* __restrict__ out, int N) {
    int node = blockIdx.x * 4 + (threadIdx.x >> 6);
    if (node >= N) return;
    int lane = threadIdx.x & 63;
    int q   = lane >> 4;
    int sub = lane & 15;
    int c0b = sub * 16;
    const char* hpc = (const char*)hb;
    int beg = offs[node], end = offs[node + 1];
    float d = 0.f;
    f32x2 acc[4] = {};
    int j = beg + q;
    for (; j + 4 < end; j += 8) {
        int cb0 = colb[j];
        int cb1 = colb[j + 4];
        float p0 = p2[j];
        float p1 = p2[j + 4];
        uint4 g0 = *(const uint4*)(hpc + (cb0 >> 1) + c0b);
        uint4 g1 = *(const uint4*)(hpc + (cb1 >> 1) + c0b);
        d += p0 + p1;
        const unsigned int* w0 = (const unsigned int*)&g0;
        const unsigned int* w1 = (const unsigned int*)&g1;
        f32x2 v0 = {p0, p0}, v1 = {p1, p1};
        #pragma unroll
        for (int i = 0; i < 4; ++i) {
            acc[i] = __builtin_elementwise_fma(v0, upk(w0[i]), acc[i]);
            acc[i] = __builtin_elementwise_fma(v1, upk(w1[i]), acc[i]);
        }
    }
    for (; j < end; j += 4) {
        int cb = colb[j];
        float p = p2[j];
        uint4 g = *(const uint4*)(hpc + (cb >> 1) + c0b);
        d += p;
        const unsigned int* w = (const unsigned int*)&g;
        f32x2 v = {p, p};
        #pragma unroll
        for (int i = 0; i < 4; ++i)
            acc[i] = __builtin_elementwise_fma(v, upk(w[i]), acc[i]);
    }
    d += __shfl_xor(d, 16);
    d += __shfl_xor(d, 32);
    #pragma unroll
    for (int i = 0; i < 4; ++i) {
        acc[i].x += __shfl_xor(acc[i].x, 16);
        acc[i].x += __shfl_xor(acc[i].x, 32);
        acc[i].y += __shfl_xor(acc[i].y, 16);
        acc[i].y += __shfl_xor(acc[i].y, 32);
    }
    if (lane < 16) {
        float inv = 1.f / d;
        int c0 = sub * 8;
        float4 bb0 = *(const float4*)(b2 + c0);
        float4 bb1 = *(const float4*)(b2 + c0 + 4);
        float av[8] = {acc[0].x, acc[0].y, acc[1].x, acc[1].y,
                       acc[2].x, acc[2].y, acc[3].x, acc[3].y};
        float bb[8] = {bb0.x, bb0.y, bb0.z, bb0.w, bb1.x, bb1.y, bb1.z, bb1.w};
        *(float4*)(out + (size_t)node * 128 + c0) =
            make_float4(av[0] * inv + bb[0], av[1] * inv + bb[1],
                        av[2] * inv + bb[2], av[3] * inv + bb[3]);
        *(float4*)(out + (size_t)node * 128 + c0 + 4) =
            make_float4(av[4] * inv + bb[4], av[5] * inv + bb[5],
                        av[6] * inv + bb[6], av[7] * inv + bb[7]);
    }
}

// ---------------- launch ----------------

extern "C" void kernel_launch(void* const* d_in, const int* in_sizes, int n_in,
                              void* d_out, int out_size, void* d_ws, size_t ws_size,
                              hipStream_t stream) {
    const float* x    = (const float*)d_in[0];
    const int*   ei   = (const int*)d_in[1];
    const float* W1   = (const float*)d_in[2];
    const float* at_s1 = (const float*)d_in[3];
    const float* at_d1 = (const float*)d_in[4];
    const float* b1   = (const float*)d_in[5];
    const float* W2   = (const float*)d_in[6];
    const float* at_s2 = (const float*)d_in[7];
    const float* at_d2 = (const float*)d_in[8];
    const float* b2   = (const float*)d_in[9];
    float* out = (float*)d_out;

    const int N  = in_sizes[0] / 128;
    const int E  = in_sizes[1] / 2;
    const int EA = E + N;

    char* ws = (char*)d_ws;
    size_t off = 0;
    auto alloc = [&](size_t bytes) -> void* {
        void* p = ws + off;
        off += (bytes + 255) & ~(size_t)255;
        return p;
    };
    unsigned short* wt1  = (unsigned short*)alloc((size_t)256 * 128 * 2);
    unsigned short* wt2  = (unsigned short*)alloc((size_t)128 * 256 * 2);
    unsigned short* h1b  = (unsigned short*)alloc((size_t)N * 256 * 2);
    unsigned short* h1ab = (unsigned short*)alloc((size_t)N * 256 * 2);
    unsigned short* h2b  = (unsigned short*)alloc((size_t)N * 128 * 2);
    float* as1 = (float*)alloc((size_t)N * 4 * 4);
    float* ad1 = (float*)alloc((size_t)N * 4 * 4);
    float* as2 = (float*)alloc((size_t)N * 4);
    float* ad2 = (float*)alloc((size_t)N * 4);
    int* deg  = (int*)alloc((size_t)N * 4);
    int* idx  = (int*)alloc((size_t)EA * 4);
    int* offs = (int*)alloc((size_t)(N + 1) * 4);
    int* bsum = (int*)alloc((size_t)1024 * 4);
    int* colb = (int*)alloc((size_t)EA * 4);
    uint2* p1 = (uint2*)alloc((size_t)EA * 8);
    float* p2 = (float*)alloc((size_t)EA * 4);

    const int nb = (N + 1 + 1023) / 1024;

    hipMemsetAsync(deg, 0, (size_t)N * 4, stream);
    cast_w_both<<<(2 * 128 * 256 + 255) / 256, 256, 0, stream>>>(W1, W2, wt1, wt2);
    degree_kernel<<<(EA + 255) / 256, 256, 0, stream>>>(ei, E, N, deg, idx);
    scan_local<<<nb, 1024, 0, stream>>>(deg, offs, bsum, N);
    scan_add<<<nb, 1024, 0, stream>>>(offs, bsum, N, nb);

    gemm1_mfma<<<(N + 63) / 64, 256, 0, stream>>>(x, wt1, at_s1, at_d1, h1b, as1, ad1, N);
    scatter_kernel<<<(EA + 255) / 256, 256, 0, stream>>>(ei, E, N, offs, idx, as1, ad1,
                                                         colb, p1);
    agg1_kernel<<<(N + 3) / 4, 256, 0, stream>>>(h1b, colb, p1, offs, b1, h1ab, N);

    gemm2_mfma<<<(N + 63) / 64, 256, 0, stream>>>(h1ab, wt2, at_s2, at_d2, h2b, as2, ad2, N);
    edgew2_kernel<<<(EA + 255) / 256, 256, 0, stream>>>(ei, E, N, offs, idx, as2, ad2, p2);
    agg2_kernel<<<(N + 3) / 4, 256, 0, stream>>>(h2b, p2, offs, colb, b2, out, N);
}

// Round 11
// 332.862 us; speedup vs baseline: 1.0748x; 1.0479x over previous
//
#include <hip/hip_runtime.h>
#include <hip/hip_bf16.h>

#define NEG_SLOPE 0.2f

typedef short bf16x8 __attribute__((ext_vector_type(8)));
typedef float f32x4 __attribute__((ext_vector_type(4)));
typedef float f32x2 __attribute__((ext_vector_type(2)));

__device__ __forceinline__ unsigned short f2bf(float f) {
    unsigned int x = __float_as_uint(f);
    unsigned int lsb = (x >> 16) & 1u;
    x += 0x7fffu + lsb;
    return (unsigned short)(x >> 16);
}
__device__ __forceinline__ f32x2 upk(unsigned int u) {
    f32x2 r;
    r.x = __uint_as_float(u << 16);
    r.y = __uint_as_float(u & 0xffff0000u);
    return r;
}
__device__ __forceinline__ unsigned short f2h(float f) {
    _Float16 h = (_Float16)f;
    return *(unsigned short*)&h;
}
__device__ __forceinline__ float h2f(unsigned short u) {
    _Float16 h = *(_Float16*)&u;
    return (float)h;
}

// per-wave exclusive-prefix of bsum[0..nb), returns prefix at (per-lane) index blk.
// ALL 64 lanes of the wave must be active when calling.
__device__ __forceinline__ int bsum_excl(const int* __restrict__ bsum, int nb, int blk) {
    int lane = threadIdx.x & 63;
    int v = (lane < nb) ? bsum[lane] : 0;
    int x = v;
    #pragma unroll
    for (int off = 1; off < 64; off <<= 1) {
        int t = __shfl_up(x, off);
        if (lane >= off) x += t;
    }
    return __shfl(x - v, blk);
}

// ---------------- prep: cast both weights + zero deg (one launch) ----------
__global__ void prep_kernel(const float* __restrict__ W1, const float* __restrict__ W2,
                            unsigned short* __restrict__ wt1, unsigned short* __restrict__ wt2,
                            int* __restrict__ deg, int N) {
    int idx = blockIdx.x * 256 + threadIdx.x;
    if (idx < 128 * 256) {
        int k = idx >> 8, n = idx & 255;
        wt1[(size_t)n * 128 + k] = f2bf(W1[idx]);
    } else if (idx < 2 * 128 * 256) {
        int j = idx - 128 * 256;
        int k = j >> 7, n = j & 127;
        wt2[(size_t)n * 256 + k] = f2bf(W2[j]);
    } else {
        int i = idx - 2 * 128 * 256;
        if (i < N) deg[i] = 0;
    }
}

// ---------------- CSR build ----------------
__global__ void degree_kernel(const int* __restrict__ ei, int E, int N,
                              int* __restrict__ deg, int* __restrict__ idx) {
    int e = blockIdx.x * blockDim.x + threadIdx.x;
    int EA = E + N;
    if (e >= EA) return;
    int dst = (e < E) ? ei[E + e] : (e - E);
    idx[e] = atomicAdd(&deg[dst], 1);
}

// per-block (1024) local exclusive scan; offs holds LOCAL prefixes + bsum totals.
// Consumers add the bsum prefix via bsum_excl().
__global__ void scan_local(const int* __restrict__ deg, int* __restrict__ offs,
                           int* __restrict__ bsum, int N) {
    __shared__ int wsum[16];
    int tid = threadIdx.x;
    int lane = tid & 63;
    int wave = tid >> 6;
    int i = blockIdx.x * 1024 + tid;
    int v = (i < N) ? deg[i] : 0;
    int x = v;
    #pragma unroll
    for (int off = 1; off < 64; off <<= 1) {
        int t = __shfl_up(x, off);
        if (lane >= off) x += t;
    }
    if (lane == 63) wsum[wave] = x;
    __syncthreads();
    if (wave == 0 && lane < 16) {
        int w = wsum[lane];
        #pragma unroll
        for (int off = 1; off < 16; off <<= 1) {
            int t = __shfl_up(w, off);
            if (lane >= off) w += t;
        }
        wsum[lane] = w;
    }
    __syncthreads();
    int wexcl = (wave > 0) ? wsum[wave - 1] : 0;
    if (i <= N) offs[i] = wexcl + x - v;
    if (tid == 0) bsum[blockIdx.x] = wsum[15];
}

// scatter (no atomics) + fused layer-1 edge-weight precompute (fp16 x4)
// + in-wave bsum prefix fixup (replaces scan_add dispatch).
__global__ void scatter_kernel(const int* __restrict__ ei, int E, int N,
                               const int* __restrict__ offs, const int* __restrict__ idx,
                               const int* __restrict__ bsum, int nb,
                               const float* __restrict__ as1, const float* __restrict__ ad1,
                               int* __restrict__ colb, uint2* __restrict__ p1) {
    int e = blockIdx.x * blockDim.x + threadIdx.x;
    int EA = E + N;
    bool act = e < EA;
    int s = 0, d = 0;
    if (act) {
        if (e < E) { s = ei[e]; d = ei[E + e]; }
        else       { s = d = e - E; }
    }
    int excl = bsum_excl(bsum, nb, d >> 10);   // all lanes participate
    if (!act) return;
    int pos = offs[d] + excl + idx[e];
    colb[pos] = s << 9;
    float4 av = *(const float4*)(as1 + s * 4);
    float4 dv = *(const float4*)(ad1 + d * 4);
    float e0 = av.x + dv.x, e1 = av.y + dv.y, e2 = av.z + dv.z, e3 = av.w + dv.w;
    e0 = (e0 > 0.f) ? e0 : NEG_SLOPE * e0;
    e1 = (e1 > 0.f) ? e1 : NEG_SLOPE * e1;
    e2 = (e2 > 0.f) ? e2 : NEG_SLOPE * e2;
    e3 = (e3 > 0.f) ? e3 : NEG_SLOPE * e3;
    uint2 q;
    q.x = (unsigned int)f2h(__expf(e0)) | ((unsigned int)f2h(__expf(e1)) << 16);
    q.y = (unsigned int)f2h(__expf(e2)) | ((unsigned int)f2h(__expf(e3)) << 16);
    p1[pos] = q;
}

// ---------------- MFMA GEMM1 + fused x-cast + fused alpha1 (R8 shape) ------
__global__ void gemm1_mfma(const float* __restrict__ A,
                           const unsigned short* __restrict__ Wt,
                           const float* __restrict__ att_s, const float* __restrict__ att_d,
                           unsigned short* __restrict__ hb,
                           float* __restrict__ as, float* __restrict__ ad, int M) {
    int wave = threadIdx.x >> 6;
    int lane = threadIdx.x & 63;
    int quad = lane >> 4;
    int l16 = lane & 15;
    int m0 = blockIdx.x * 64 + wave * 16;
    int rowc = min(m0 + l16, M - 1);
    bf16x8 a[4];
    const float* ap = A + (size_t)rowc * 128 + quad * 8;
    #pragma unroll
    for (int kc = 0; kc < 4; ++kc) {
        float4 f0 = *(const float4*)(ap + kc * 32);
        float4 f1 = *(const float4*)(ap + kc * 32 + 4);
        bf16x8 v;
        v[0] = (short)f2bf(f0.x); v[1] = (short)f2bf(f0.y);
        v[2] = (short)f2bf(f0.z); v[3] = (short)f2bf(f0.w);
        v[4] = (short)f2bf(f1.x); v[5] = (short)f2bf(f1.y);
        v[6] = (short)f2bf(f1.z); v[7] = (short)f2bf(f1.w);
        a[kc] = v;
    }
    f32x4 acc[16];
    #pragma unroll
    for (int nt = 0; nt < 16; ++nt) {
        f32x4 c = {0.f, 0.f, 0.f, 0.f};
        const unsigned short* bp = Wt + (size_t)(nt * 16 + l16) * 128 + quad * 8;
        #pragma unroll
        for (int kc = 0; kc < 4; ++kc) {
            bf16x8 b = *(const bf16x8*)(bp + kc * 32);
            c = __builtin_amdgcn_mfma_f32_16x16x32_bf16(a[kc], b, c, 0, 0, 0);
        }
        acc[nt] = c;
    }
    float asv[16], adv[16];
    #pragma unroll
    for (int nt = 0; nt < 16; ++nt) {
        asv[nt] = att_s[nt * 16 + l16];
        adv[nt] = att_d[nt * 16 + l16];
    }
    int srow0 = m0 + quad * 4;
    #pragma unroll
    for (int r = 0; r < 4; ++r) {
        int srow = srow0 + r;
        bool ok = srow < M;
        if (ok) {
            #pragma unroll
            for (int nt = 0; nt < 16; ++nt)
                hb[(size_t)srow * 256 + nt * 16 + l16] = f2bf(acc[nt][r]);
        }
        #pragma unroll
        for (int h = 0; h < 4; ++h) {
            float ps = acc[4 * h][r] * asv[4 * h] + acc[4 * h + 1][r] * asv[4 * h + 1]
                     + acc[4 * h + 2][r] * asv[4 * h + 2] + acc[4 * h + 3][r] * asv[4 * h + 3];
            float pd = acc[4 * h][r] * adv[4 * h] + acc[4 * h + 1][r] * adv[4 * h + 1]
                     + acc[4 * h + 2][r] * adv[4 * h + 2] + acc[4 * h + 3][r] * adv[4 * h + 3];
            #pragma unroll
            for (int off = 1; off < 16; off <<= 1) {
                ps += __shfl_xor(ps, off);
                pd += __shfl_xor(pd, off);
            }
            if (ok && l16 == 0) {
                as[srow * 4 + h] = ps;
                ad[srow * 4 + h] = pd;
            }
        }
    }
}

// ---------------- MFMA GEMM2 + fused alpha2 (R8 shape) ----------------
__global__ void gemm2_mfma(const unsigned short* __restrict__ Ab,
                           const unsigned short* __restrict__ Wt,
                           const float* __restrict__ att_s, const float* __restrict__ att_d,
                           unsigned short* __restrict__ hb,
                           float* __restrict__ as, float* __restrict__ ad, int M) {
    int wave = threadIdx.x >> 6;
    int lane = threadIdx.x & 63;
    int quad = lane >> 4;
    int l16 = lane & 15;
    int m0 = blockIdx.x * 64 + wave * 16;
    int rowc = min(m0 + l16, M - 1);
    bf16x8 a[8];
    const unsigned short* ap = Ab + (size_t)rowc * 256 + quad * 8;
    #pragma unroll
    for (int kc = 0; kc < 8; ++kc) a[kc] = *(const bf16x8*)(ap + kc * 32);
    f32x4 acc[8];
    #pragma unroll
    for (int nt = 0; nt < 8; ++nt) {
        f32x4 c = {0.f, 0.f, 0.f, 0.f};
        const unsigned short* bp = Wt + (size_t)(nt * 16 + l16) * 256 + quad * 8;
        #pragma unroll
        for (int kc = 0; kc < 8; ++kc) {
            bf16x8 b = *(const bf16x8*)(bp + kc * 32);
            c = __builtin_amdgcn_mfma_f32_16x16x32_bf16(a[kc], b, c, 0, 0, 0);
        }
        acc[nt] = c;
    }
    float asv[8], adv[8];
    #pragma unroll
    for (int nt = 0; nt < 8; ++nt) {
        asv[nt] = att_s[nt * 16 + l16];
        adv[nt] = att_d[nt * 16 + l16];
    }
    int srow0 = m0 + quad * 4;
    #pragma unroll
    for (int r = 0; r < 4; ++r) {
        int srow = srow0 + r;
        bool ok = srow < M;
        if (ok) {
            #pragma unroll
            for (int nt = 0; nt < 8; ++nt)
                hb[(size_t)srow * 128 + nt * 16 + l16] = f2bf(acc[nt][r]);
        }
        float ps = 0.f, pd = 0.f;
        #pragma unroll
        for (int nt = 0; nt < 8; ++nt) {
            ps = fmaf(acc[nt][r], asv[nt], ps);
            pd = fmaf(acc[nt][r], adv[nt], pd);
        }
        #pragma unroll
        for (int off = 1; off < 16; off <<= 1) {
            ps += __shfl_xor(ps, off);
            pd += __shfl_xor(pd, off);
        }
        if (ok && l16 == 0) { as[srow] = ps; ad[srow] = pd; }
    }
}

// ---------------- layer-1 aggregation (R8 structure + bsum fixup) ----------
__global__ void agg1_kernel(const unsigned short* __restrict__ hb,
                            const int* __restrict__ colb, const uint2* __restrict__ p1,
                            const int* __restrict__ offs,
                            const int* __restrict__ bsum, int nb,
                            const float* __restrict__ b1,
                            unsigned short* __restrict__ out, int N) {
    int node = blockIdx.x * 4 + (threadIdx.x >> 6);
    if (node >= N) return;                       // wave-uniform
    int lane = threadIdx.x & 63;
    int half = lane >> 5;
    int sub  = lane & 31;
    int head = sub >> 3;
    int c0b = sub * 16;
    const char* hpc = (const char*)hb;
    int beg = offs[node] + bsum_excl(bsum, nb, node >> 10);
    int end = offs[node + 1] + bsum_excl(bsum, nb, (node + 1) >> 10);
    float d = 0.f;
    f32x2 acc[4] = {};
    int j = beg + half;
    for (; j + 6 < end; j += 8) {
        int o0 = colb[j] + c0b;
        int o1 = colb[j + 2] + c0b;
        int o2 = colb[j + 4] + c0b;
        int o3 = colb[j + 6] + c0b;
        uint2 q0 = p1[j];
        uint2 q1 = p1[j + 2];
        uint2 q2 = p1[j + 4];
        uint2 q3 = p1[j + 6];
        uint4 g0 = *(const uint4*)(hpc + o0);
        uint4 g1 = *(const uint4*)(hpc + o1);
        uint4 g2 = *(const uint4*)(hpc + o2);
        uint4 g3 = *(const uint4*)(hpc + o3);
        unsigned int u0 = (head & 2) ? q0.y : q0.x;
        unsigned int u1 = (head & 2) ? q1.y : q1.x;
        unsigned int u2 = (head & 2) ? q2.y : q2.x;
        unsigned int u3 = (head & 2) ? q3.y : q3.x;
        float p0 = h2f((unsigned short)((head & 1) ? (u0 >> 16) : (u0 & 0xffff)));
        float p1v = h2f((unsigned short)((head & 1) ? (u1 >> 16) : (u1 & 0xffff)));
        float p2 = h2f((unsigned short)((head & 1) ? (u2 >> 16) : (u2 & 0xffff)));
        float p3 = h2f((unsigned short)((head & 1) ? (u3 >> 16) : (u3 & 0xffff)));
        d += (p0 + p1v) + (p2 + p3);
        const unsigned int* w0 = (const unsigned int*)&g0;
        const unsigned int* w1 = (const unsigned int*)&g1;
        const unsigned int* w2 = (const unsigned int*)&g2;
        const unsigned int* w3 = (const unsigned int*)&g3;
        f32x2 v0 = {p0, p0}, v1 = {p1v, p1v}, v2 = {p2, p2}, v3 = {p3, p3};
        #pragma unroll
        for (int i = 0; i < 4; ++i) {
            acc[i] = __builtin_elementwise_fma(v0, upk(w0[i]), acc[i]);
            acc[i] = __builtin_elementwise_fma(v1, upk(w1[i]), acc[i]);
            acc[i] = __builtin_elementwise_fma(v2, upk(w2[i]), acc[i]);
            acc[i] = __builtin_elementwise_fma(v3, upk(w3[i]), acc[i]);
        }
    }
    for (; j < end; j += 2) {
        int o = colb[j] + c0b;
        uint2 q = p1[j];
        uint4 g = *(const uint4*)(hpc + o);
        unsigned int u = (head & 2) ? q.y : q.x;
        float p = h2f((unsigned short)((head & 1) ? (u >> 16) : (u & 0xffff)));
        d += p;
        const unsigned int* w = (const unsigned int*)&g;
        f32x2 v = {p, p};
        #pragma unroll
        for (int i = 0; i < 4; ++i)
            acc[i] = __builtin_elementwise_fma(v, upk(w[i]), acc[i]);
    }
    d += __shfl_xor(d, 32);
    #pragma unroll
    for (int i = 0; i < 4; ++i) {
        acc[i].x += __shfl_xor(acc[i].x, 32);
        acc[i].y += __shfl_xor(acc[i].y, 32);
    }
    if (half == 0) {
        float inv = 1.f / d;
        int c0 = sub * 8;
        float4 bb0 = *(const float4*)(b1 + c0);
        float4 bb1 = *(const float4*)(b1 + c0 + 4);
        float av[8] = {acc[0].x, acc[0].y, acc[1].x, acc[1].y,
                       acc[2].x, acc[2].y, acc[3].x, acc[3].y};
        float bb[8] = {bb0.x, bb0.y, bb0.z, bb0.w, bb1.x, bb1.y, bb1.z, bb1.w};
        unsigned short o[8];
        #pragma unroll
        for (int i = 0; i < 8; ++i) {
            float v = av[i] * inv + bb[i];
            v = (v > 0.f) ? v : (__expf(v) - 1.f);
            o[i] = f2bf(v);
        }
        ushort4 q0 = {o[0], o[1], o[2], o[3]};
        ushort4 q1 = {o[4], o[5], o[6], o[7]};
        *(ushort4*)(out + (size_t)node * 256 + c0) = q0;
        *(ushort4*)(out + (size_t)node * 256 + c0 + 4) = q1;
    }
}

// ---------------- layer-2 aggregation (R8 structure + bsum fixup) ----------
__global__ void agg2_kernel(const unsigned short* __restrict__ hb,
                            const float* __restrict__ as,
                            const float* __restrict__ ad,
                            const int* __restrict__ offs, const int* __restrict__ colb,
                            const int* __restrict__ bsum, int nb,
                            const float* __restrict__ b2,
                            float* __restrict__ out, int N) {
    int node = blockIdx.x * 4 + (threadIdx.x >> 6);
    if (node >= N) return;                       // wave-uniform
    int lane = threadIdx.x & 63;
    int q   = lane >> 4;
    int sub = lane & 15;
    int c0b = sub * 16;
    const char* hpc = (const char*)hb;
    float adv = ad[node];
    int beg = offs[node] + bsum_excl(bsum, nb, node >> 10);
    int end = offs[node + 1] + bsum_excl(bsum, nb, (node + 1) >> 10);
    float d = 0.f;
    f32x2 acc[4] = {};
    int j = beg + q;
    for (; j + 4 < end; j += 8) {
        int cb0 = colb[j];
        int cb1 = colb[j + 4];
        uint4 g0 = *(const uint4*)(hpc + (cb0 >> 1) + c0b);
        uint4 g1 = *(const uint4*)(hpc + (cb1 >> 1) + c0b);
        float e0 = as[cb0 >> 9] + adv;
        float e1 = as[cb1 >> 9] + adv;
        e0 = (e0 > 0.f) ? e0 : NEG_SLOPE * e0;
        e1 = (e1 > 0.f) ? e1 : NEG_SLOPE * e1;
        float p0 = __expf(e0), p1 = __expf(e1);
        d += p0 + p1;
        const unsigned int* w0 = (const unsigned int*)&g0;
        const unsigned int* w1 = (const unsigned int*)&g1;
        f32x2 v0 = {p0, p0}, v1 = {p1, p1};
        #pragma unroll
        for (int i = 0; i < 4; ++i) {
            acc[i] = __builtin_elementwise_fma(v0, upk(w0[i]), acc[i]);
            acc[i] = __builtin_elementwise_fma(v1, upk(w1[i]), acc[i]);
        }
    }
    for (; j < end; j += 4) {
        int cb = colb[j];
        uint4 g = *(const uint4*)(hpc + (cb >> 1) + c0b);
        float e = as[cb >> 9] + adv;
        e = (e > 0.f) ? e : NEG_SLOPE * e;
        float p = __expf(e);
        d += p;
        const unsigned int* w = (const unsigned int*)&g;
        f32x2 v = {p, p};
        #pragma unroll
        for (int i = 0; i < 4; ++i)
            acc[i] = __builtin_elementwise_fma(v, upk(w[i]), acc[i]);
    }
    d += __shfl_xor(d, 16);
    d += __shfl_xor(d, 32);
    #pragma unroll
    for (int i = 0; i < 4; ++i) {
        acc[i].x += __shfl_xor(acc[i].x, 16);
        acc[i].x += __shfl_xor(acc[i].x, 32);
        acc[i].y += __shfl_xor(acc[i].y, 16);
        acc[i].y += __shfl_xor(acc[i].y, 32);
    }
    if (lane < 16) {
        float inv = 1.f / d;
        int c0 = sub * 8;
        float4 bb0 = *(const float4*)(b2 + c0);
        float4 bb1 = *(const float4*)(b2 + c0 + 4);
        float av[8] = {acc[0].x, acc[0].y, acc[1].x, acc[1].y,
                       acc[2].x, acc[2].y, acc[3].x, acc[3].y};
        float bb[8] = {bb0.x, bb0.y, bb0.z, bb0.w, bb1.x, bb1.y, bb1.z, bb1.w};
        *(float4*)(out + (size_t)node * 128 + c0) =
            make_float4(av[0] * inv + bb[0], av[1] * inv + bb[1],
                        av[2] * inv + bb[2], av[3] * inv + bb[3]);
        *(float4*)(out + (size_t)node * 128 + c0 + 4) =
            make_float4(av[4] * inv + bb[4], av[5] * inv + bb[5],
                        av[6] * inv + bb[6], av[7] * inv + bb[7]);
    }
}

// ---------------- launch (8 dispatches) ----------------

extern "C" void kernel_launch(void* const* d_in, const int* in_sizes, int n_in,
                              void* d_out, int out_size, void* d_ws, size_t ws_size,
                              hipStream_t stream) {
    const float* x    = (const float*)d_in[0];
    const int*   ei   = (const int*)d_in[1];
    const float* W1   = (const float*)d_in[2];
    const float* at_s1 = (const float*)d_in[3];
    const float* at_d1 = (const float*)d_in[4];
    const float* b1   = (const float*)d_in[5];
    const float* W2   = (const float*)d_in[6];
    const float* at_s2 = (const float*)d_in[7];
    const float* at_d2 = (const float*)d_in[8];
    const float* b2   = (const float*)d_in[9];
    float* out = (float*)d_out;

    const int N  = in_sizes[0] / 128;
    const int E  = in_sizes[1] / 2;
    const int EA = E + N;

    char* ws = (char*)d_ws;
    size_t off = 0;
    auto alloc = [&](size_t bytes) -> void* {
        void* p = ws + off;
        off += (bytes + 255) & ~(size_t)255;
        return p;
    };
    unsigned short* wt1  = (unsigned short*)alloc((size_t)256 * 128 * 2);
    unsigned short* wt2  = (unsigned short*)alloc((size_t)128 * 256 * 2);
    unsigned short* h1b  = (unsigned short*)alloc((size_t)N * 256 * 2);
    unsigned short* h1ab = (unsigned short*)alloc((size_t)N * 256 * 2);
    unsigned short* h2b  = (unsigned short*)alloc((size_t)N * 128 * 2);
    float* as1 = (float*)alloc((size_t)N * 4 * 4);
    float* ad1 = (float*)alloc((size_t)N * 4 * 4);
    float* as2 = (float*)alloc((size_t)N * 4);
    float* ad2 = (float*)alloc((size_t)N * 4);
    int* deg  = (int*)alloc((size_t)N * 4);
    int* idx  = (int*)alloc((size_t)EA * 4);
    int* offs = (int*)alloc((size_t)(N + 1) * 4);
    int* bsum = (int*)alloc((size_t)1024 * 4);
    int* colb = (int*)alloc((size_t)EA * 4);
    uint2* p1 = (uint2*)alloc((size_t)EA * 8);

    const int nb = (N + 1 + 1023) / 1024;

    prep_kernel<<<(2 * 128 * 256 + N + 255) / 256, 256, 0, stream>>>(W1, W2, wt1, wt2, deg, N);
    degree_kernel<<<(EA + 255) / 256, 256, 0, stream>>>(ei, E, N, deg, idx);
    scan_local<<<nb, 1024, 0, stream>>>(deg, offs, bsum, N);

    gemm1_mfma<<<(N + 63) / 64, 256, 0, stream>>>(x, wt1, at_s1, at_d1, h1b, as1, ad1, N);
    scatter_kernel<<<(EA + 255) / 256, 256, 0, stream>>>(ei, E, N, offs, idx, bsum, nb,
                                                         as1, ad1, colb, p1);
    agg1_kernel<<<(N + 3) / 4, 256, 0, stream>>>(h1b, colb, p1, offs, bsum, nb, b1, h1ab, N);

    gemm2_mfma<<<(N + 63) / 64, 256, 0, stream>>>(h1ab, wt2, at_s2, at_d2, h2b, as2, ad2, N);
    agg2_kernel<<<(N + 3) / 4, 256, 0, stream>>>(h2b, as2, ad2, offs, colb, bsum, nb,
                                                 b2, out, N);
}

// Round 12
// 325.763 us; speedup vs baseline: 1.0982x; 1.0218x over previous
//
#include <hip/hip_runtime.h>
#include <hip/hip_bf16.h>

#define NEG_SLOPE 0.2f

typedef short bf16x8 __attribute__((ext_vector_type(8)));
typedef float f32x4 __attribute__((ext_vector_type(4)));
typedef float f32x2 __attribute__((ext_vector_type(2)));

__device__ __forceinline__ unsigned short f2bf(float f) {
    unsigned int x = __float_as_uint(f);
    unsigned int lsb = (x >> 16) & 1u;
    x += 0x7fffu + lsb;
    return (unsigned short)(x >> 16);
}
__device__ __forceinline__ f32x2 upk(unsigned int u) {
    f32x2 r;
    r.x = __uint_as_float(u << 16);
    r.y = __uint_as_float(u & 0xffff0000u);
    return r;
}
__device__ __forceinline__ unsigned short f2h(float f) {
    _Float16 h = (_Float16)f;
    return *(unsigned short*)&h;
}
__device__ __forceinline__ float h2f(unsigned short u) {
    _Float16 h = *(_Float16*)&u;
    return (float)h;
}

// per-wave exclusive-prefix of bsum[0..nb); ALL 64 lanes must be active.
__device__ __forceinline__ int bsum_excl(const int* __restrict__ bsum, int nb, int blk) {
    int lane = threadIdx.x & 63;
    int v = (lane < nb) ? bsum[lane] : 0;
    int x = v;
    #pragma unroll
    for (int off = 1; off < 64; off <<= 1) {
        int t = __shfl_up(x, off);
        if (lane >= off) x += t;
    }
    return __shfl(x - v, blk);
}

// ---------------- prep: cast both weights + zero deg (one launch) ----------
__global__ void prep_kernel(const float* __restrict__ W1, const float* __restrict__ W2,
                            unsigned short* __restrict__ wt1, unsigned short* __restrict__ wt2,
                            int* __restrict__ deg, int N) {
    int idx = blockIdx.x * 256 + threadIdx.x;
    if (idx < 128 * 256) {
        int k = idx >> 8, n = idx & 255;
        wt1[(size_t)n * 128 + k] = f2bf(W1[idx]);
    } else if (idx < 2 * 128 * 256) {
        int j = idx - 128 * 256;
        int k = j >> 7, n = j & 127;
        wt2[(size_t)n * 256 + k] = f2bf(W2[j]);
    } else {
        int i = idx - 2 * 128 * 256;
        if (i < N) deg[i] = 0;
    }
}

// ---------------- CSR build ----------------
__global__ void degree_kernel(const int* __restrict__ ei, int E, int N,
                              int* __restrict__ deg, int* __restrict__ idx) {
    int e = blockIdx.x * blockDim.x + threadIdx.x;
    int EA = E + N;
    if (e >= EA) return;
    int dst = (e < E) ? ei[E + e] : (e - E);
    idx[e] = atomicAdd(&deg[dst], 1);
}

// per-block (1024) local exclusive scan; offs = LOCAL prefixes, bsum = totals.
__global__ void scan_local(const int* __restrict__ deg, int* __restrict__ offs,
                           int* __restrict__ bsum, int N) {
    __shared__ int wsum[16];
    int tid = threadIdx.x;
    int lane = tid & 63;
    int wave = tid >> 6;
    int i = blockIdx.x * 1024 + tid;
    int v = (i < N) ? deg[i] : 0;
    int x = v;
    #pragma unroll
    for (int off = 1; off < 64; off <<= 1) {
        int t = __shfl_up(x, off);
        if (lane >= off) x += t;
    }
    if (lane == 63) wsum[wave] = x;
    __syncthreads();
    if (wave == 0 && lane < 16) {
        int w = wsum[lane];
        #pragma unroll
        for (int off = 1; off < 16; off <<= 1) {
            int t = __shfl_up(w, off);
            if (lane >= off) w += t;
        }
        wsum[lane] = w;
    }
    __syncthreads();
    int wexcl = (wave > 0) ? wsum[wave - 1] : 0;
    if (i <= N) offs[i] = wexcl + x - v;
    if (tid == 0) bsum[blockIdx.x] = wsum[15];
}

// scatter (no atomics) + fused layer-1 edge-weight precompute (fp16 x4)
__global__ void scatter_kernel(const int* __restrict__ ei, int E, int N,
                               const int* __restrict__ offs, const int* __restrict__ idx,
                               const int* __restrict__ bsum, int nb,
                               const float* __restrict__ as1, const float* __restrict__ ad1,
                               int* __restrict__ colb, uint2* __restrict__ p1) {
    int e = blockIdx.x * blockDim.x + threadIdx.x;
    int EA = E + N;
    bool act = e < EA;
    int s = 0, d = 0;
    if (act) {
        if (e < E) { s = ei[e]; d = ei[E + e]; }
        else       { s = d = e - E; }
    }
    int excl = bsum_excl(bsum, nb, d >> 10);
    if (!act) return;
    int pos = offs[d] + excl + idx[e];
    colb[pos] = s << 9;
    float4 av = *(const float4*)(as1 + s * 4);
    float4 dv = *(const float4*)(ad1 + d * 4);
    float e0 = av.x + dv.x, e1 = av.y + dv.y, e2 = av.z + dv.z, e3 = av.w + dv.w;
    e0 = (e0 > 0.f) ? e0 : NEG_SLOPE * e0;
    e1 = (e1 > 0.f) ? e1 : NEG_SLOPE * e1;
    e2 = (e2 > 0.f) ? e2 : NEG_SLOPE * e2;
    e3 = (e3 > 0.f) ? e3 : NEG_SLOPE * e3;
    uint2 q;
    q.x = (unsigned int)f2h(__expf(e0)) | ((unsigned int)f2h(__expf(e1)) << 16);
    q.y = (unsigned int)f2h(__expf(e2)) | ((unsigned int)f2h(__expf(e3)) << 16);
    p1[pos] = q;
}

// ---------------- MFMA GEMM1 + fused x-cast + fused alpha1 ----------------
__global__ void gemm1_mfma(const float* __restrict__ A,
                           const unsigned short* __restrict__ Wt,
                           const float* __restrict__ att_s, const float* __restrict__ att_d,
                           unsigned short* __restrict__ hb,
                           float* __restrict__ as, float* __restrict__ ad, int M) {
    int wave = threadIdx.x >> 6;
    int lane = threadIdx.x & 63;
    int quad = lane >> 4;
    int l16 = lane & 15;
    int m0 = blockIdx.x * 64 + wave * 16;
    int rowc = min(m0 + l16, M - 1);
    bf16x8 a[4];
    const float* ap = A + (size_t)rowc * 128 + quad * 8;
    #pragma unroll
    for (int kc = 0; kc < 4; ++kc) {
        float4 f0 = *(const float4*)(ap + kc * 32);
        float4 f1 = *(const float4*)(ap + kc * 32 + 4);
        bf16x8 v;
        v[0] = (short)f2bf(f0.x); v[1] = (short)f2bf(f0.y);
        v[2] = (short)f2bf(f0.z); v[3] = (short)f2bf(f0.w);
        v[4] = (short)f2bf(f1.x); v[5] = (short)f2bf(f1.y);
        v[6] = (short)f2bf(f1.z); v[7] = (short)f2bf(f1.w);
        a[kc] = v;
    }
    f32x4 acc[16];
    #pragma unroll
    for (int nt = 0; nt < 16; ++nt) {
        f32x4 c = {0.f, 0.f, 0.f, 0.f};
        const unsigned short* bp = Wt + (size_t)(nt * 16 + l16) * 128 + quad * 8;
        #pragma unroll
        for (int kc = 0; kc < 4; ++kc) {
            bf16x8 b = *(const bf16x8*)(bp + kc * 32);
            c = __builtin_amdgcn_mfma_f32_16x16x32_bf16(a[kc], b, c, 0, 0, 0);
        }
        acc[nt] = c;
    }
    float asv[16], adv[16];
    #pragma unroll
    for (int nt = 0; nt < 16; ++nt) {
        asv[nt] = att_s[nt * 16 + l16];
        adv[nt] = att_d[nt * 16 + l16];
    }
    int srow0 = m0 + quad * 4;
    #pragma unroll
    for (int r = 0; r < 4; ++r) {
        int srow = srow0 + r;
        bool ok = srow < M;
        if (ok) {
            #pragma unroll
            for (int nt = 0; nt < 16; ++nt)
                hb[(size_t)srow * 256 + nt * 16 + l16] = f2bf(acc[nt][r]);
        }
        #pragma unroll
        for (int h = 0; h < 4; ++h) {
            float ps = acc[4 * h][r] * asv[4 * h] + acc[4 * h + 1][r] * asv[4 * h + 1]
                     + acc[4 * h + 2][r] * asv[4 * h + 2] + acc[4 * h + 3][r] * asv[4 * h + 3];
            float pd = acc[4 * h][r] * adv[4 * h] + acc[4 * h + 1][r] * adv[4 * h + 1]
                     + acc[4 * h + 2][r] * adv[4 * h + 2] + acc[4 * h + 3][r] * adv[4 * h + 3];
            #pragma unroll
            for (int off = 1; off < 16; off <<= 1) {
                ps += __shfl_xor(ps, off);
                pd += __shfl_xor(pd, off);
            }
            if (ok && l16 == 0) {
                as[srow * 4 + h] = ps;
                ad[srow * 4 + h] = pd;
            }
        }
    }
}

// ---------------- FUSED: layer-1 aggregation + GEMM2 + alpha2 ----------------
// Block = 16 nodes. Phase 1: each wave aggregates 4 nodes (R11 agg1 inner loop),
// ELU'd bf16 rows -> LDS tile. Phase 2: 16x256 @ 256x128 MFMA from LDS,
// writes h2b + as2/ad2. Replaces agg1 + gemm2 dispatches and the h1ab round-trip.
__global__ void agg1_gemm2(const unsigned short* __restrict__ hb,
                           const int* __restrict__ colb, const uint2* __restrict__ p1,
                           const int* __restrict__ offs,
                           const int* __restrict__ bsum, int nb,
                           const float* __restrict__ b1,
                           const unsigned short* __restrict__ Wt,
                           const float* __restrict__ att_s, const float* __restrict__ att_d,
                           unsigned short* __restrict__ h2b,
                           float* __restrict__ as2, float* __restrict__ ad2, int N) {
    __shared__ unsigned short Atile[16][264];   // +8 pad: 2-way-free LDS banks
    __shared__ float asP[16], adP[16];
    int tid = threadIdx.x;
    int wave = tid >> 6;
    int lane = tid & 63;
    if (tid < 16) { asP[tid] = 0.f; adP[tid] = 0.f; }
    int half = lane >> 5;
    int sub  = lane & 31;
    int head = sub >> 3;
    int c0b = sub * 16;
    const char* hpc = (const char*)hb;
    int node0 = blockIdx.x * 16;

    // ---- phase 1: aggregate ----
    for (int t = 0; t < 4; ++t) {
        int lrow = wave * 4 + t;
        int node = min(node0 + lrow, N - 1);
        int beg = offs[node] + bsum_excl(bsum, nb, node >> 10);
        int end = offs[node + 1] + bsum_excl(bsum, nb, (node + 1) >> 10);
        float d = 0.f;
        f32x2 acc[4] = {};
        int j = beg + half;
        for (; j + 6 < end; j += 8) {
            int o0 = colb[j] + c0b;
            int o1 = colb[j + 2] + c0b;
            int o2 = colb[j + 4] + c0b;
            int o3 = colb[j + 6] + c0b;
            uint2 q0 = p1[j];
            uint2 q1 = p1[j + 2];
            uint2 q2 = p1[j + 4];
            uint2 q3 = p1[j + 6];
            uint4 g0 = *(const uint4*)(hpc + o0);
            uint4 g1 = *(const uint4*)(hpc + o1);
            uint4 g2 = *(const uint4*)(hpc + o2);
            uint4 g3 = *(const uint4*)(hpc + o3);
            unsigned int u0 = (head & 2) ? q0.y : q0.x;
            unsigned int u1 = (head & 2) ? q1.y : q1.x;
            unsigned int u2 = (head & 2) ? q2.y : q2.x;
            unsigned int u3 = (head & 2) ? q3.y : q3.x;
            float p0 = h2f((unsigned short)((head & 1) ? (u0 >> 16) : (u0 & 0xffff)));
            float p1v = h2f((unsigned short)((head & 1) ? (u1 >> 16) : (u1 & 0xffff)));
            float p2 = h2f((unsigned short)((head & 1) ? (u2 >> 16) : (u2 & 0xffff)));
            float p3 = h2f((unsigned short)((head & 1) ? (u3 >> 16) : (u3 & 0xffff)));
            d += (p0 + p1v) + (p2 + p3);
            const unsigned int* w0 = (const unsigned int*)&g0;
            const unsigned int* w1 = (const unsigned int*)&g1;
            const unsigned int* w2 = (const unsigned int*)&g2;
            const unsigned int* w3 = (const unsigned int*)&g3;
            f32x2 v0 = {p0, p0}, v1 = {p1v, p1v}, v2 = {p2, p2}, v3 = {p3, p3};
            #pragma unroll
            for (int i = 0; i < 4; ++i) {
                acc[i] = __builtin_elementwise_fma(v0, upk(w0[i]), acc[i]);
                acc[i] = __builtin_elementwise_fma(v1, upk(w1[i]), acc[i]);
                acc[i] = __builtin_elementwise_fma(v2, upk(w2[i]), acc[i]);
                acc[i] = __builtin_elementwise_fma(v3, upk(w3[i]), acc[i]);
            }
        }
        for (; j < end; j += 2) {
            int o = colb[j] + c0b;
            uint2 q = p1[j];
            uint4 g = *(const uint4*)(hpc + o);
            unsigned int u = (head & 2) ? q.y : q.x;
            float p = h2f((unsigned short)((head & 1) ? (u >> 16) : (u & 0xffff)));
            d += p;
            const unsigned int* w = (const unsigned int*)&g;
            f32x2 v = {p, p};
            #pragma unroll
            for (int i = 0; i < 4; ++i)
                acc[i] = __builtin_elementwise_fma(v, upk(w[i]), acc[i]);
        }
        d += __shfl_xor(d, 32);
        #pragma unroll
        for (int i = 0; i < 4; ++i) {
            acc[i].x += __shfl_xor(acc[i].x, 32);
            acc[i].y += __shfl_xor(acc[i].y, 32);
        }
        if (half == 0) {
            float inv = 1.f / d;
            int c0 = sub * 8;
            float4 bb0 = *(const float4*)(b1 + c0);
            float4 bb1 = *(const float4*)(b1 + c0 + 4);
            float av[8] = {acc[0].x, acc[0].y, acc[1].x, acc[1].y,
                           acc[2].x, acc[2].y, acc[3].x, acc[3].y};
            float bb[8] = {bb0.x, bb0.y, bb0.z, bb0.w, bb1.x, bb1.y, bb1.z, bb1.w};
            unsigned short o[8];
            #pragma unroll
            for (int i = 0; i < 8; ++i) {
                float v = av[i] * inv + bb[i];
                v = (v > 0.f) ? v : (__expf(v) - 1.f);
                o[i] = f2bf(v);
            }
            ushort4 q0 = {o[0], o[1], o[2], o[3]};
            ushort4 q1 = {o[4], o[5], o[6], o[7]};
            *(ushort4*)&Atile[lrow][c0] = q0;
            *(ushort4*)&Atile[lrow][c0 + 4] = q1;
        }
    }
    __syncthreads();

    // ---- phase 2: 16x128 = Atile(16x256) @ wt2; wave owns n-tiles 2w,2w+1 ----
    int quad = lane >> 4;
    int l16 = lane & 15;
    bf16x8 a[8];
    #pragma unroll
    for (int kc = 0; kc < 8; ++kc)
        a[kc] = *(const bf16x8*)&Atile[l16][kc * 32 + quad * 8];
    int nt0 = wave * 2;
    f32x4 acc2[2];
    #pragma unroll
    for (int i = 0; i < 2; ++i) {
        f32x4 c = {0.f, 0.f, 0.f, 0.f};
        const unsigned short* bp = Wt + (size_t)((nt0 + i) * 16 + l16) * 256 + quad * 8;
        #pragma unroll
        for (int kc = 0; kc < 8; ++kc) {
            bf16x8 b = *(const bf16x8*)(bp + kc * 32);
            c = __builtin_amdgcn_mfma_f32_16x16x32_bf16(a[kc], b, c, 0, 0, 0);
        }
        acc2[i] = c;
    }
    float s0 = att_s[nt0 * 16 + l16], s1 = att_s[(nt0 + 1) * 16 + l16];
    float d0 = att_d[nt0 * 16 + l16], d1 = att_d[(nt0 + 1) * 16 + l16];
    #pragma unroll
    for (int r = 0; r < 4; ++r) {
        int row = quad * 4 + r;
        int grow = node0 + row;
        if (grow < N) {
            h2b[(size_t)grow * 128 + nt0 * 16 + l16] = f2bf(acc2[0][r]);
            h2b[(size_t)grow * 128 + (nt0 + 1) * 16 + l16] = f2bf(acc2[1][r]);
        }
        float ps = acc2[0][r] * s0 + acc2[1][r] * s1;
        float pd = acc2[0][r] * d0 + acc2[1][r] * d1;
        #pragma unroll
        for (int off = 1; off < 16; off <<= 1) {
            ps += __shfl_xor(ps, off);
            pd += __shfl_xor(pd, off);
        }
        if (l16 == 0) {
            atomicAdd(&asP[row], ps);
            atomicAdd(&adP[row], pd);
        }
    }
    __syncthreads();
    if (tid < 16 && node0 + tid < N) {
        as2[node0 + tid] = asP[tid];
        ad2[node0 + tid] = adP[tid];
    }
}

// ---------------- layer-2 aggregation (R11 structure) ----------------
__global__ void agg2_kernel(const unsigned short* __restrict__ hb,
                            const float* __restrict__ as,
                            const float* __restrict__ ad,
                            const int* __restrict__ offs, const int* __restrict__ colb,
                            const int* __restrict__ bsum, int nb,
                            const float* __restrict__ b2,
                            float* __restrict__ out, int N) {
    int node = blockIdx.x * 4 + (threadIdx.x >> 6);
    if (node >= N) return;
    int lane = threadIdx.x & 63;
    int q   = lane >> 4;
    int sub = lane & 15;
    int c0b = sub * 16;
    const char* hpc = (const char*)hb;
    float adv = ad[node];
    int beg = offs[node] + bsum_excl(bsum, nb, node >> 10);
    int end = offs[node + 1] + bsum_excl(bsum, nb, (node + 1) >> 10);
    float d = 0.f;
    f32x2 acc[4] = {};
    int j = beg + q;
    for (; j + 4 < end; j += 8) {
        int cb0 = colb[j];
        int cb1 = colb[j + 4];
        uint4 g0 = *(const uint4*)(hpc + (cb0 >> 1) + c0b);
        uint4 g1 = *(const uint4*)(hpc + (cb1 >> 1) + c0b);
        float e0 = as[cb0 >> 9] + adv;
        float e1 = as[cb1 >> 9] + adv;
        e0 = (e0 > 0.f) ? e0 : NEG_SLOPE * e0;
        e1 = (e1 > 0.f) ? e1 : NEG_SLOPE * e1;
        float p0 = __expf(e0), p1 = __expf(e1);
        d += p0 + p1;
        const unsigned int* w0 = (const unsigned int*)&g0;
        const unsigned int* w1 = (const unsigned int*)&g1;
        f32x2 v0 = {p0, p0}, v1 = {p1, p1};
        #pragma unroll
        for (int i = 0; i < 4; ++i) {
            acc[i] = __builtin_elementwise_fma(v0, upk(w0[i]), acc[i]);
            acc[i] = __builtin_elementwise_fma(v1, upk(w1[i]), acc[i]);
        }
    }
    for (; j < end; j += 4) {
        int cb = colb[j];
        uint4 g = *(const uint4*)(hpc + (cb >> 1) + c0b);
        float e = as[cb >> 9] + adv;
        e = (e > 0.f) ? e : NEG_SLOPE * e;
        float p = __expf(e);
        d += p;
        const unsigned int* w = (const unsigned int*)&g;
        f32x2 v = {p, p};
        #pragma unroll
        for (int i = 0; i < 4; ++i)
            acc[i] = __builtin_elementwise_fma(v, upk(w[i]), acc[i]);
    }
    d += __shfl_xor(d, 16);
    d += __shfl_xor(d, 32);
    #pragma unroll
    for (int i = 0; i < 4; ++i) {
        acc[i].x += __shfl_xor(acc[i].x, 16);
        acc[i].x += __shfl_xor(acc[i].x, 32);
        acc[i].y += __shfl_xor(acc[i].y, 16);
        acc[i].y += __shfl_xor(acc[i].y, 32);
    }
    if (lane < 16) {
        float inv = 1.f / d;
        int c0 = sub * 8;
        float4 bb0 = *(const float4*)(b2 + c0);
        float4 bb1 = *(const float4*)(b2 + c0 + 4);
        float av[8] = {acc[0].x, acc[0].y, acc[1].x, acc[1].y,
                       acc[2].x, acc[2].y, acc[3].x, acc[3].y};
        float bb[8] = {bb0.x, bb0.y, bb0.z, bb0.w, bb1.x, bb1.y, bb1.z, bb1.w};
        *(float4*)(out + (size_t)node * 128 + c0) =
            make_float4(av[0] * inv + bb[0], av[1] * inv + bb[1],
                        av[2] * inv + bb[2], av[3] * inv + bb[3]);
        *(float4*)(out + (size_t)node * 128 + c0 + 4) =
            make_float4(av[4] * inv + bb[4], av[5] * inv + bb[5],
                        av[6] * inv + bb[6], av[7] * inv + bb[7]);
    }
}

// ---------------- launch (7 dispatches) ----------------

extern "C" void kernel_launch(void* const* d_in, const int* in_sizes, int n_in,
                              void* d_out, int out_size, void* d_ws, size_t ws_size,
                              hipStream_t stream) {
    const float* x    = (const float*)d_in[0];
    const int*   ei   = (const int*)d_in[1];
    const float* W1   = (const float*)d_in[2];
    const float* at_s1 = (const float*)d_in[3];
    const float* at_d1 = (const float*)d_in[4];
    const float* b1   = (const float*)d_in[5];
    const float* W2   = (const float*)d_in[6];
    const float* at_s2 = (const float*)d_in[7];
    const float* at_d2 = (const float*)d_in[8];
    const float* b2   = (const float*)d_in[9];
    float* out = (float*)d_out;

    const int N  = in_sizes[0] / 128;
    const int E  = in_sizes[1] / 2;
    const int EA = E + N;

    char* ws = (char*)d_ws;
    size_t off = 0;
    auto alloc = [&](size_t bytes) -> void* {
        void* p = ws + off;
        off += (bytes + 255) & ~(size_t)255;
        return p;
    };
    unsigned short* wt1  = (unsigned short*)alloc((size_t)256 * 128 * 2);
    unsigned short* wt2  = (unsigned short*)alloc((size_t)128 * 256 * 2);
    unsigned short* h1b  = (unsigned short*)alloc((size_t)N * 256 * 2);
    unsigned short* h2b  = (unsigned short*)alloc((size_t)N * 128 * 2);
    float* as1 = (float*)alloc((size_t)N * 4 * 4);
    float* ad1 = (float*)alloc((size_t)N * 4 * 4);
    float* as2 = (float*)alloc((size_t)N * 4);
    float* ad2 = (float*)alloc((size_t)N * 4);
    int* deg  = (int*)alloc((size_t)N * 4);
    int* idx  = (int*)alloc((size_t)EA * 4);
    int* offs = (int*)alloc((size_t)(N + 1) * 4);
    int* bsum = (int*)alloc((size_t)1024 * 4);
    int* colb = (int*)alloc((size_t)EA * 4);
    uint2* p1 = (uint2*)alloc((size_t)EA * 8);

    const int nb = (N + 1 + 1023) / 1024;

    prep_kernel<<<(2 * 128 * 256 + N + 255) / 256, 256, 0, stream>>>(W1, W2, wt1, wt2, deg, N);
    degree_kernel<<<(EA + 255) / 256, 256, 0, stream>>>(ei, E, N, deg, idx);
    scan_local<<<nb, 1024, 0, stream>>>(deg, offs, bsum, N);

    gemm1_mfma<<<(N + 63) / 64, 256, 0, stream>>>(x, wt1, at_s1, at_d1, h1b, as1, ad1, N);
    scatter_kernel<<<(EA + 255) / 256, 256, 0, stream>>>(ei, E, N, offs, idx, bsum, nb,
                                                         as1, ad1, colb, p1);
    agg1_gemm2<<<(N + 15) / 16, 256, 0, stream>>>(h1b, colb, p1, offs, bsum, nb, b1,
                                                  wt2, at_s2, at_d2, h2b, as2, ad2, N);
    agg2_kernel<<<(N + 3) / 4, 256, 0, stream>>>(h2b, as2, ad2, offs, colb, bsum, nb,
                                                 b2, out, N);
}